// Round 13
// baseline (643.121 us; speedup 1.0000x reference)
//
#include <hip/hip_runtime.h>
#include <hip/hip_bf16.h>
#include <math.h>

typedef __hip_bfloat16 bf16;
typedef __bf16 bf16x8 __attribute__((ext_vector_type(8)));
typedef __bf16 bf16x2v __attribute__((ext_vector_type(2)));
typedef float f32x4 __attribute__((ext_vector_type(4)));

#define NN 50000
#define EE 400000
#define FIN 262
#define KP1 288   /* FIN padded to multiple of 32 */
#define HID 128
#define NH 4
#define C1 512   /* HID*NH */
#define NGR 16
#define SCAN_NB ((NN + 255) / 256)   /* 196 */

__device__ __forceinline__ float b2f(bf16 x){ return __bfloat162float(x); }
__device__ __forceinline__ bf16 f2b(float x){ return __float2bfloat16(x); }
__device__ __forceinline__ float lrelu(float v){ return v >= 0.f ? v : 0.2f * v; }
__device__ __forceinline__ float eluf(float v){ return v > 0.f ? v : expm1f(v); }

__global__ void zero_words(unsigned int* __restrict__ p, int n) {
  int i = blockIdx.x * 256 + threadIdx.x;
  if (i < n) p[i] = 0u;
}

// ================= MFMA GEMM: C(M,N) = A(M,K) @ B(K,N) =================
// 2-deep register pipeline: at iter t, loads for tile t+2 issue into the set
// freed by tile t's store; the LDS-write of tile t+1 uses regs loaded a full
// iteration earlier (~1300cy in flight -> counted-vmcnt wait is free).
// LDS 32 KiB, chunk-XOR swizzle on write+read. Optional fused bn (sc/sh) and
// per-row dual dot epilogue (es/ed; LDS-reduced, no atomics).
__global__ __launch_bounds__(256)
void gemm_mfma(const bf16* __restrict__ A, const bf16* __restrict__ Bt,
               bf16* __restrict__ C, int M, int K, int Ncols,
               const float* __restrict__ sc, const float* __restrict__ sh,
               const float* __restrict__ av, const float* __restrict__ bv,
               float* __restrict__ esp, float* __restrict__ edp, int dstride) {
  __shared__ __align__(16) __bf16 As[2][128 * 32];
  __shared__ __align__(16) __bf16 Bs[2][128 * 32];
  int bm = blockIdx.y * 128, bn = blockIdx.x * 128;
  int tid = threadIdx.x;
  int wave = tid >> 6, lane = tid & 63;
  int quad = lane >> 4, l16 = lane & 15;
  int wm = (wave >> 1) * 64, wn = (wave & 1) * 64;
  int rowA = (tid * 8) >> 5;          // 0..63 (each thread also covers rowA+64)
  int colT = (tid * 8) & 31;
  int swW = ((rowA >> 1) & 3) << 3;   // write-side chunk swizzle (same for rowA+64)
  int gm0 = bm + rowA, gm1 = bm + rowA + 64;
  int gn0 = bn + rowA, gn1 = bn + rowA + 64;
  const uint4 zz = {0u, 0u, 0u, 0u};

  f32x4 acc[4][4];
  #pragma unroll
  for (int i = 0; i < 4; ++i)
    #pragma unroll
    for (int j = 0; j < 4; ++j)
      acc[i][j] = (f32x4){0.f, 0.f, 0.f, 0.f};

  // two staging register sets (ping-pong, statically named)
  uint4 Pa0, Pa1, Pb0, Pb1;
  uint4 Qa0, Qa1, Qb0, Qb1;

  auto xf = [&](uint4 v, int kb) -> uint4 {   // kb = k0 + colT
    if (sc == nullptr) return v;
    bf16x8 a8 = *(bf16x8*)&v;
    float4 c0 = *(const float4*)(sc + kb);
    float4 c1 = *(const float4*)(sc + kb + 4);
    float4 h0 = *(const float4*)(sh + kb);
    float4 h1 = *(const float4*)(sh + kb + 4);
    bf16x8 t8;
    t8[0] = (__bf16)((float)a8[0] * c0.x + h0.x);
    t8[1] = (__bf16)((float)a8[1] * c0.y + h0.y);
    t8[2] = (__bf16)((float)a8[2] * c0.z + h0.z);
    t8[3] = (__bf16)((float)a8[3] * c0.w + h0.w);
    t8[4] = (__bf16)((float)a8[4] * c1.x + h1.x);
    t8[5] = (__bf16)((float)a8[5] * c1.y + h1.y);
    t8[6] = (__bf16)((float)a8[6] * c1.z + h1.z);
    t8[7] = (__bf16)((float)a8[7] * c1.w + h1.w);
    return *(uint4*)&t8;
  };
  auto ldS = [&](uint4& r0, uint4& r1, uint4& r2, uint4& r3, int k0) {
    r0 = (gm0 < M) ? *(const uint4*)(A + (size_t)gm0 * K + k0 + colT) : zz;
    r1 = (gm1 < M) ? *(const uint4*)(A + (size_t)gm1 * K + k0 + colT) : zz;
    r2 = (gn0 < Ncols) ? *(const uint4*)(Bt + (size_t)gn0 * K + k0 + colT) : zz;
    r3 = (gn1 < Ncols) ? *(const uint4*)(Bt + (size_t)gn1 * K + k0 + colT) : zz;
  };
  auto stS = [&](uint4 r0, uint4 r1, uint4 r2, uint4 r3, int buf, int k0) {
    int cw = colT ^ swW;
    *(uint4*)(&As[buf][rowA * 32 + cw])        = xf(r0, k0 + colT);
    *(uint4*)(&As[buf][(rowA + 64) * 32 + cw]) = xf(r1, k0 + colT);
    *(uint4*)(&Bs[buf][rowA * 32 + cw])        = r2;
    *(uint4*)(&Bs[buf][(rowA + 64) * 32 + cw]) = r3;
  };
  auto mm = [&](int cur) {
    bf16x8 af[4], bfr[4];
    #pragma unroll
    for (int i = 0; i < 4; ++i) {
      int r = wm + i * 16 + l16;
      af[i] = *(const bf16x8*)(&As[cur][r * 32 + ((quad << 3) ^ (((r >> 1) & 3) << 3))]);
    }
    #pragma unroll
    for (int j = 0; j < 4; ++j) {
      int r = wn + j * 16 + l16;
      bfr[j] = *(const bf16x8*)(&Bs[cur][r * 32 + ((quad << 3) ^ (((r >> 1) & 3) << 3))]);
    }
    #pragma unroll
    for (int i = 0; i < 4; ++i)
      #pragma unroll
      for (int j = 0; j < 4; ++j)
        acc[i][j] = __builtin_amdgcn_mfma_f32_16x16x32_bf16(af[i], bfr[j], acc[i][j], 0, 0, 0);
  };

  int nt = K >> 5;   // >= 4 for all call sites
  ldS(Pa0, Pa1, Pb0, Pb1, 0);
  stS(Pa0, Pa1, Pb0, Pb1, 0, 0);
  ldS(Qa0, Qa1, Qb0, Qb1, 32);       // tile 1 in flight across the barrier
  __syncthreads();

  for (int t = 0; t < nt; t += 2) {
    {  // even body: compute tile t; load t+2 into P (free); store t+1 from Q
      int cur = t & 1;
      if (t + 2 < nt) ldS(Pa0, Pa1, Pb0, Pb1, (t + 2) << 5);
      mm(cur);
      if (t + 1 < nt) stS(Qa0, Qa1, Qb0, Qb1, cur ^ 1, (t + 1) << 5);
      __syncthreads();
    }
    if (t + 1 < nt) {  // odd body: compute t+1; load t+3 into Q; store t+2 from P
      int cur = (t + 1) & 1;
      if (t + 3 < nt) ldS(Qa0, Qa1, Qb0, Qb1, (t + 3) << 5);
      mm(cur);
      if (t + 2 < nt) stS(Pa0, Pa1, Pb0, Pb1, cur ^ 1, (t + 2) << 5);
      __syncthreads();
    }
  }

  // C write
  #pragma unroll
  for (int i = 0; i < 4; ++i) {
    #pragma unroll
    for (int r = 0; r < 4; ++r) {
      int gm = bm + wm + i * 16 + quad * 4 + r;
      if (gm >= M) continue;
      #pragma unroll
      for (int j = 0; j < 4; ++j) {
        int gn = bn + wn + j * 16 + l16;
        C[(size_t)gm * Ncols + gn] = f2b(acc[i][j][r]);
      }
    }
  }

  // fused edot epilogue: per-row dual dot over this block's 128 cols.
  // LDS reduction in dead As space; direct stores (no atomics).
  if (esp) {
    float* red = (float*)&As[0][0];   // 128 rows x {waveHalf} x {es,ed} = 2 KB
    float avj[4], bvj[4];
    #pragma unroll
    for (int j = 0; j < 4; ++j) {
      int gn = bn + wn + j * 16 + l16;
      avj[j] = av[gn]; bvj[j] = bv[gn];
    }
    #pragma unroll
    for (int i = 0; i < 4; ++i)
      #pragma unroll
      for (int r = 0; r < 4; ++r) {
        float pa = 0.f, pb = 0.f;
        #pragma unroll
        for (int j = 0; j < 4; ++j) {
          float v = acc[i][j][r];
          pa += v * avj[j]; pb += v * bvj[j];
        }
        #pragma unroll
        for (int off = 8; off > 0; off >>= 1) {
          pa += __shfl_xor(pa, off);
          pb += __shfl_xor(pb, off);
        }
        if (l16 == 0) {
          int rl = wm + i * 16 + quad * 4 + r;   // 0..127
          red[rl * 4 + (wave & 1) * 2 + 0] = pa;
          red[rl * 4 + (wave & 1) * 2 + 1] = pb;
        }
      }
    __syncthreads();
    if (tid < 128) {
      int gm = bm + tid;
      if (gm < M) {
        int hoff = (dstride == 4) ? (bn >> 7) : 0;
        esp[gm * dstride + hoff] = red[tid * 4 + 0] + red[tid * 4 + 2];
        edp[gm * dstride + hoff] = red[tid * 4 + 1] + red[tid * 4 + 3];
      }
    }
  }
}

// ---- merged prep: conv_x | b1t | b2t | bpt (range-dispatched) ----
#define PR0 (NN * KP1)                 /* 14,400,000 */
#define PR1 (PR0 + C1 * KP1)           /* 14,547,456 */
#define PR2 (PR1 + HID * C1)           /* 14,612,992 */
#define PR3 (PR2 + 256 * HID)          /* 14,645,760 */
__global__ void prep_all(const float* __restrict__ x, const float* __restrict__ W1,
                         const float* __restrict__ W2, const float* __restrict__ epw1,
                         bf16* __restrict__ xb, bf16* __restrict__ B1t,
                         bf16* __restrict__ B2t, bf16* __restrict__ BPt) {
  int i = blockIdx.x * 256 + threadIdx.x;
  if (i < PR0) {
    int row = i / KP1, col = i - row * KP1;
    xb[i] = (col < FIN) ? f2b(x[(size_t)row * FIN + col]) : f2b(0.f);
  } else if (i < PR1) {
    int j = i - PR0;
    int n = j / KP1, k = j - n * KP1;   // n = h*128 + o
    int h = n >> 7, o = n & 127;
    B1t[j] = (k < FIN) ? f2b(W1[((size_t)h * FIN + k) * HID + o]) : f2b(0.f);
  } else if (i < PR2) {
    int j = i - PR1;
    int n = j >> 9, k = j & 511;
    B2t[j] = f2b(W2[(size_t)k * HID + n]);
  } else if (i < PR3) {
    int j = i - PR2;
    int n = j >> 7, k = j & 127;
    float v = (n < 128) ? epw1[(size_t)k * HID + n]
                        : epw1[(size_t)(128 + k) * HID + (n - 128)];
    BPt[j] = f2b(v);
  }
}

// ---------------- CSR build ----------------
__global__ void count_kernel(const int* __restrict__ dst, int* __restrict__ deg, int E) {
  int e = blockIdx.x * blockDim.x + threadIdx.x;
  if (e >= E) return;
  int d = dst[e];
  if ((unsigned)d < NN) atomicAdd(&deg[d], 1);
}

__global__ void scan_p1(const int* __restrict__ deg, int* __restrict__ bsum) {
  __shared__ int s[256];
  int t = threadIdx.x;
  int i = blockIdx.x * 256 + t;
  s[t] = (i < NN) ? deg[i] : 0;
  __syncthreads();
  #pragma unroll
  for (int off = 128; off > 0; off >>= 1) {
    if (t < off) s[t] += s[t + off];
    __syncthreads();
  }
  if (t == 0) bsum[blockIdx.x] = s[0];
}
// parallel Hillis-Steele exclusive scan over block sums
__global__ void scan_p2(const int* __restrict__ bsum, int* __restrict__ boff,
                        int* __restrict__ total_out) {
  __shared__ int s[256];
  int t = threadIdx.x;
  int v = (t < SCAN_NB) ? bsum[t] : 0;
  s[t] = v;
  __syncthreads();
  #pragma unroll
  for (int off = 1; off < 256; off <<= 1) {
    int add = (t >= off) ? s[t - off] : 0;
    __syncthreads();
    s[t] += add;
    __syncthreads();
  }
  if (t < SCAN_NB) boff[t] = s[t] - v;   // exclusive
  if (t == 255) total_out[0] = s[255];   // rowptr[NN]
}
__global__ void scan_p3(const int* __restrict__ deg, const int* __restrict__ boff,
                        int* __restrict__ rowptr, int* __restrict__ cursor) {
  __shared__ int s[256];
  int t = threadIdx.x;
  int i = blockIdx.x * 256 + t;
  int v = (i < NN) ? deg[i] : 0;
  s[t] = v;
  __syncthreads();
  #pragma unroll
  for (int off = 1; off < 256; off <<= 1) {
    int add = (t >= off) ? s[t - off] : 0;
    __syncthreads();
    s[t] += add;
    __syncthreads();
  }
  if (i < NN) {
    int pos = boff[blockIdx.x] + s[t] - v;   // exclusive
    rowptr[i] = pos;
    cursor[i] = pos;
  }
}

__global__ void scatter_kernel(const int* __restrict__ src, const int* __restrict__ dst,
                               int* __restrict__ cursor, int* __restrict__ csr_s,
                               int* __restrict__ csr_d, int* __restrict__ csr_e, int E) {
  int e = blockIdx.x * blockDim.x + threadIdx.x;
  if (e >= E) return;
  int d = dst[e];
  if ((unsigned)d >= NN) return;
  int s = src[e]; if ((unsigned)s >= NN) s = 0;
  int p = atomicAdd(&cursor[d], 1);
  if ((unsigned)p < (unsigned)E) { csr_s[p] = s; csr_d[p] = d; csr_e[p] = e; }
}

// ---- layer-1 aggregate: wave per node, 8/4/1 tiered loop, logits inline (no max-sub) ----
__global__ __launch_bounds__(256, 6)
void agg1_all(const int* __restrict__ csr_s, const int* __restrict__ rowptr,
              const float* __restrict__ es, const float* __restrict__ ed,
              const bf16* __restrict__ Wh1, bf16* __restrict__ h1) {
  int wid = threadIdx.x >> 6, lane = threadIdx.x & 63;
  int node = blockIdx.x * 4 + wid;
  if (node >= NN) return;
  int b = rowptr[node], e = rowptr[node + 1];
  if (b < 0) b = 0; if (e > EE) e = EE;
  int h = lane >> 4;
  float edh = ed[node * 4 + h];
  float sum = 0.f;
  float acc[8] = {};
  const bf16* W = Wh1 + lane * 8;
  int j = b;
  for (; j + 8 <= e; j += 8) {
    int s_[8];
    #pragma unroll
    for (int i = 0; i < 8; ++i) s_[i] = csr_s[j + i];
    float w[8];
    bf16x8 r[8];
    #pragma unroll
    for (int i = 0; i < 8; ++i) {
      w[i] = es[s_[i] * 4 + h];
      r[i] = *(const bf16x8*)(W + (size_t)s_[i] * C1);
    }
    #pragma unroll
    for (int i = 0; i < 8; ++i) {
      float p = __expf(lrelu(w[i] + edh));
      sum += p;
      #pragma unroll
      for (int k = 0; k < 8; ++k) acc[k] += p * (float)r[i][k];
    }
  }
  if (j + 4 <= e) {
    int s_[4];
    #pragma unroll
    for (int i = 0; i < 4; ++i) s_[i] = csr_s[j + i];
    float w[4];
    bf16x8 r[4];
    #pragma unroll
    for (int i = 0; i < 4; ++i) {
      w[i] = es[s_[i] * 4 + h];
      r[i] = *(const bf16x8*)(W + (size_t)s_[i] * C1);
    }
    #pragma unroll
    for (int i = 0; i < 4; ++i) {
      float p = __expf(lrelu(w[i] + edh));
      sum += p;
      #pragma unroll
      for (int k = 0; k < 8; ++k) acc[k] += p * (float)r[i][k];
    }
    j += 4;
  }
  for (; j < e; ++j) {
    int s0 = csr_s[j];
    float p = __expf(lrelu(es[s0 * 4 + h] + edh));
    bf16x8 r0 = *(const bf16x8*)(W + (size_t)s0 * C1);
    sum += p;
    #pragma unroll
    for (int k = 0; k < 8; ++k) acc[k] += p * (float)r0[k];
  }
  float scale = 1.f / (sum + 1e-8f);
  bf16x8 o;
  #pragma unroll
  for (int k = 0; k < 8; ++k) o[k] = (__bf16)eluf(acc[k] * scale);
  *(bf16x8*)(h1 + (size_t)node * C1 + lane * 8) = o;
}

// ---- layer-2 aggregate (H=1): 16-lane group per node, logits inline;
//      attention output fused (lane-parallel pass over the node's edges) ----
__global__ __launch_bounds__(256, 8)
void agg2_all(const int* __restrict__ csr_s, const int* __restrict__ csr_e,
              const int* __restrict__ rowptr,
              const float* __restrict__ es, const float* __restrict__ ed,
              const bf16* __restrict__ Wh2, bf16* __restrict__ h2p,
              float* __restrict__ out_attn) {
  int tid = threadIdx.x;
  int l16 = tid & 15;
  int node = blockIdx.x * 16 + (tid >> 4);
  if (node >= NN) return;
  int b = rowptr[node], e = rowptr[node + 1];
  if (b < 0) b = 0; if (e > EE) e = EE;
  float edn = ed[node];
  float sum = 0.f;
  float acc[8] = {};
  const bf16* W = Wh2 + l16 * 8;
  int j = b;
  for (; j + 4 <= e; j += 4) {
    int s_[4];
    #pragma unroll
    for (int i = 0; i < 4; ++i) s_[i] = csr_s[j + i];
    float w[4];
    bf16x8 r[4];
    #pragma unroll
    for (int i = 0; i < 4; ++i) {
      w[i] = es[s_[i]];
      r[i] = *(const bf16x8*)(W + (size_t)s_[i] * HID);
    }
    #pragma unroll
    for (int i = 0; i < 4; ++i) {
      float p = __expf(lrelu(w[i] + edn));
      sum += p;
      #pragma unroll
      for (int k = 0; k < 8; ++k) acc[k] += p * (float)r[i][k];
    }
  }
  for (; j < e; ++j) {
    int s0 = csr_s[j];
    float p = __expf(lrelu(es[s0] + edn));
    bf16x8 r0 = *(const bf16x8*)(W + (size_t)s0 * HID);
    sum += p;
    #pragma unroll
    for (int k = 0; k < 8; ++k) acc[k] += p * (float)r0[k];
  }
  float scale = 1.f / (sum + 1e-8f);
  bf16x8 o;
  #pragma unroll
  for (int k = 0; k < 8; ++k) o[k] = (__bf16)eluf(acc[k] * scale);
  *(bf16x8*)(h2p + (size_t)node * HID + l16 * 8) = o;
  for (int t = b + l16; t < e; t += 16) {
    int s0 = csr_s[t];
    int eid = csr_e[t];
    float p = __expf(lrelu(es[s0] + edn));
    if ((unsigned)eid < EE) out_attn[eid] = p * scale;
  }
}

// ---- read-only per-column stats: blockDim == C, thread-per-column ----
__global__ void stats_ro(const bf16* __restrict__ X, float* __restrict__ cs,
                         float* __restrict__ cq, int Nrows, int C) {
  int c = threadIdx.x;
  int rpb = (Nrows + gridDim.x - 1) / gridDim.x;
  int r0 = blockIdx.x * rpb, r1 = min(r0 + rpb, Nrows);
  float s = 0.f, s2 = 0.f;
  for (int r = r0; r < r1; ++r) {
    float v = b2f(X[(size_t)r * C + c]);
    s += v; s2 += v * v;
  }
  atomicAdd(&cs[c], s);
  atomicAdd(&cq[c], s2);
}

// ---- bn coefficients: sc = gamma*rstd, sh = beta - mu*gamma*rstd ----
__global__ void bn_coef(const float* __restrict__ cs, const float* __restrict__ cq,
                        const float* __restrict__ gamma, const float* __restrict__ beta,
                        float* __restrict__ sc, float* __restrict__ sh, int C, float invN) {
  int c = blockIdx.x * 256 + threadIdx.x;
  if (c >= C) return;
  float mu = cs[c] * invN;
  float var = cq[c] * invN - mu * mu;
  float g = rsqrtf(fmaxf(var, 0.f) + 1e-5f) * gamma[c];
  sc[c] = g;
  sh[c] = beta[c] - mu * g;
}

// ---- fused bn-apply (f32 out) + global mean pool (post-bn sums) ----
__global__ __launch_bounds__(256)
void poolbn_kernel(const bf16* __restrict__ h2p, const int* __restrict__ batch,
                   const float* __restrict__ sc, const float* __restrict__ sh,
                   float* __restrict__ out_h2, float* __restrict__ pooled) {
  int t = threadIdx.x;
  int f = t & 127, half = t >> 7;
  float scf = sc[f], shf = sh[f];
  int r0 = blockIdx.x * 32;
  int g_cur = -1;
  float acc = 0.f;
  #pragma unroll
  for (int i = 0; i < 16; ++i) {
    int r = r0 + half + 2 * i;
    if (r >= NN) break;
    int g = batch[r]; if ((unsigned)g >= NGR) g = 0;
    float v = b2f(h2p[(size_t)r * HID + f]) * scf + shf;
    out_h2[(size_t)r * HID + f] = v;
    if (g != g_cur) {
      if (g_cur >= 0) atomicAdd(&pooled[g_cur * HID + f], acc);
      g_cur = g; acc = 0.f;
    }
    acc += v;
  }
  if (g_cur >= 0) atomicAdd(&pooled[g_cur * HID + f], acc);
}

// ---- classifier (tiny, single block); counts computed in-kernel ----
__global__ void cls_kernel(const float* __restrict__ pooled, const int* __restrict__ batch,
                           const float* __restrict__ w1, const float* __restrict__ b1,
                           const float* __restrict__ w2, const float* __restrict__ b2,
                           float* __restrict__ out) {
  __shared__ float repr[NGR * HID];
  __shared__ float hid[NGR * 64];
  __shared__ float scnt[NGR];
  int t = threadIdx.x;  // 128
  if (t < NGR) {
    int g = t;
    int a = 0, b = NN;
    while (a < b) { int m = (a + b) >> 1; if (batch[m] < g) a = m + 1; else b = m; }
    int lb = a;
    a = 0; b = NN;
    while (a < b) { int m = (a + b) >> 1; if (batch[m] <= g) a = m + 1; else b = m; }
    scnt[t] = (float)(a - lb);
  }
  __syncthreads();
  for (int i = t; i < NGR * HID; i += 128) {
    int g = i >> 7;
    repr[i] = pooled[i] / fmaxf(scnt[g], 1.f);
  }
  __syncthreads();
  for (int i = t; i < NGR * 64; i += 128) {
    int g = i >> 6, j = i & 63;
    float s = b1[j];
    for (int c = 0; c < HID; ++c) s += repr[g * HID + c] * w1[c * 64 + j];
    hid[i] = fmaxf(s, 0.f);
  }
  __syncthreads();
  if (t < NGR * 2) {
    int g = t >> 1, k = t & 1;
    float s = b2[k];
    for (int j = 0; j < 64; ++j) s += hid[g * 64 + j] * w2[j * 2 + k];
    out[t] = s;
  }
}

// ---- edge importance from fused PQ (N,256): CSR order, 16-lane group per edge ----
__global__ __launch_bounds__(256)
void eimp_kernel(const int* __restrict__ csr_s, const int* __restrict__ csr_d,
                 const int* __restrict__ csr_e, const bf16* __restrict__ PQ,
                 const float* __restrict__ b1, const float* __restrict__ w2,
                 const float* __restrict__ b2, float* __restrict__ out) {
  int tid = threadIdx.x;
  int wave = tid >> 6, lane = tid & 63;
  int g = lane >> 4, l16 = lane & 15;
  int slot = blockIdx.x * 16 + wave * 4 + g;
  if (slot >= EE) return;
  int s = csr_s[slot]; if ((unsigned)s >= NN) s = 0;
  int d = csr_d[slot]; if ((unsigned)d >= NN) d = 0;
  int e = csr_e[slot]; if ((unsigned)e >= EE) return;
  bf16x8 p = *(const bf16x8*)(PQ + (size_t)s * 256 + l16 * 8);
  bf16x8 q = *(const bf16x8*)(PQ + (size_t)d * 256 + 128 + l16 * 8);
  float acc = 0.f;
  #pragma unroll
  for (int r = 0; r < 8; ++r) {
    int jj = l16 * 8 + r;
    float hh = (float)p[r] + (float)q[r] + b1[jj];
    hh = fmaxf(hh, 0.f);
    acc += hh * w2[jj];
  }
  #pragma unroll
  for (int off = 8; off > 0; off >>= 1) acc += __shfl_xor(acc, off);
  if (l16 == 0) {
    float z = acc + b2[0];
    out[e] = 1.f / (1.f + expf(-z));
  }
}

extern "C" void kernel_launch(void* const* d_in, const int* in_sizes, int n_in,
                              void* d_out, int out_size, void* d_ws, size_t ws_size,
                              hipStream_t stream) {
  const float* x      = (const float*)d_in[0];
  const int*   ei     = (const int*)d_in[1];
  const int*   batch  = (const int*)d_in[2];
  const float* W1     = (const float*)d_in[3];
  const float* a_src1 = (const float*)d_in[4];
  const float* a_dst1 = (const float*)d_in[5];
  const float* W2     = (const float*)d_in[6];
  const float* a_src2 = (const float*)d_in[7];
  const float* a_dst2 = (const float*)d_in[8];
  const float* bn1_g  = (const float*)d_in[9];
  const float* bn1_b  = (const float*)d_in[10];
  const float* bn2_g  = (const float*)d_in[11];
  const float* bn2_b  = (const float*)d_in[12];
  const float* cls_w1 = (const float*)d_in[13];
  const float* cls_b1 = (const float*)d_in[14];
  const float* cls_w2 = (const float*)d_in[15];
  const float* cls_b2 = (const float*)d_in[16];
  const float* ep_w1  = (const float*)d_in[17];
  const float* ep_b1  = (const float*)d_in[18];
  const float* ep_w2  = (const float*)d_in[19];
  const float* ep_b2  = (const float*)d_in[20];

  const int* srcp = ei;
  const int* dstp = ei + EE;

  // ---- workspace layout (bytes), peak ~110.5 MB, hazard-checked ----
  char* base = (char*)d_ws;
  bf16* xb   = (bf16*)(base);
  bf16* h1   = (bf16*)(base);
  bf16* Wh1  = (bf16*)(base + 51200000);
  bf16* Wh2  = (bf16*)(base + 51200000);
  bf16* PQ   = (bf16*)(base + 51200000);
  bf16* h2p  = (bf16*)(base + 76800000);
  float* es1   = (float*)(base + 102400000);    // (N,4) fully written by gemm1 epilogue
  float* ed1   = (float*)(base + 103200000);    // (N,4)
  float* es2   = (float*)(base + 104000000);    // (N)
  float* ed2   = (float*)(base + 104200000);    // (N)
  int*   deg   = (int*)(base + 104400000);      // (N)   [zero region start]
  float* stats = (float*)(base + 104600000);    // 3344 floats -> end 104,613,376
  float* cs1 = stats,        *cq1 = stats + 512;
  float* cs2 = stats + 1024, *cq2 = stats + 1152;
  float* pooled = stats + 1280;                 // 16*128
  float* sc1   = (float*)(base + 104613376);    // (512)
  float* sh1   = (float*)(base + 104615424);    // (512)
  float* sc2   = (float*)(base + 104617472);    // (128)
  float* sh2   = (float*)(base + 104617984);    // (128) -> 104,618,496
  int*   cursor= (int*)(base + 104818496);      // (N)
  int*   rowptr= (int*)(base + 105018496);      // (N+1) -> 105,218,500
  int*   bsum  = (int*)(base + 105218560);      // 256 + 256
  int*   boff  = bsum + 256;
  int*   csr_s = (int*)(base + 105220608);      // (E)
  int*   csr_d = (int*)(base + 106820608);      // (E)
  int*   csr_e = (int*)(base + 108420608);      // (E)
  bf16*  B1t   = (bf16*)(base + 110020608);     // (512,288)
  bf16*  B2t   = (bf16*)(base + 110315520);     // (128,512)
  bf16*  BPt   = (bf16*)(base + 110446592);     // (256,128) -> ends 110,512,128

  float* out        = (float*)d_out;
  float* out_logits = out;                          // 32
  float* out_h2     = out + 32;                     // N*128
  float* out_imp    = out + 32 + (size_t)NN * HID;  // E
  float* out_attn   = out_imp + EE;                 // E

  // zero deg+stats in one call (contiguous; 213,376 B = 53,344 words)
  zero_words<<<(53344 + 255) / 256, 256, 0, stream>>>((unsigned int*)deg, 53344);

  // merged prep: bf16 conversions / transposes
  prep_all<<<(PR3 + 255) / 256, 256, 0, stream>>>(x, W1, W2, ep_w1, xb, B1t, B2t, BPt);

  // CSR by destination; parallel 3-phase scan
  count_kernel<<<(EE + 255) / 256, 256, 0, stream>>>(dstp, deg, EE);
  scan_p1<<<SCAN_NB, 256, 0, stream>>>(deg, bsum);
  scan_p2<<<1, 256, 0, stream>>>(bsum, boff, rowptr + NN);
  scan_p3<<<SCAN_NB, 256, 0, stream>>>(deg, boff, rowptr, cursor);
  scatter_kernel<<<(EE + 255) / 256, 256, 0, stream>>>(srcp, dstp, cursor,
                                                       csr_s, csr_d, csr_e, EE);

  // ---- layer 1: GEMM (edot fused via LDS, no atomics) + aggregate ----
  dim3 g1(C1 / 128, (NN + 127) / 128);
  gemm_mfma<<<g1, 256, 0, stream>>>(xb, B1t, Wh1, NN, KP1, C1, nullptr, nullptr,
                                    a_src1, a_dst1, es1, ed1, 4);
  agg1_all<<<(NN + 3) / 4, 256, 0, stream>>>(csr_s, rowptr, es1, ed1, Wh1, h1);

  // read-only stats on ELU'd h1; bn folded into gemm2's A-staging
  stats_ro<<<400, C1, 0, stream>>>(h1, cs1, cq1, NN, C1);
  bn_coef<<<2, 256, 0, stream>>>(cs1, cq1, bn1_g, bn1_b, sc1, sh1, C1, 1.f / NN);

  // ---- layer 2 (edot fused into gemm2; attn output fused into agg2) ----
  dim3 g2(1, (NN + 127) / 128);
  gemm_mfma<<<g2, 256, 0, stream>>>(h1, B2t, Wh2, NN, C1, HID, sc1, sh1,
                                    a_src2, a_dst2, es2, ed2, 1);
  agg2_all<<<(NN + 15) / 16, 256, 0, stream>>>(csr_s, csr_e, rowptr, es2, ed2,
                                               Wh2, h2p, out_attn);

  stats_ro<<<400, HID, 0, stream>>>(h2p, cs2, cq2, NN, HID);
  bn_coef<<<1, 256, 0, stream>>>(cs2, cq2, bn2_g, bn2_b, sc2, sh2, HID, 1.f / NN);

  // fused bn-out + pool (post-bn sums), then classifier (counts in-kernel)
  poolbn_kernel<<<(NN + 31) / 32, 256, 0, stream>>>(h2p, batch, sc2, sh2, out_h2, pooled);
  cls_kernel<<<1, 128, 0, stream>>>(pooled, batch, cls_w1, cls_b1, cls_w2, cls_b2,
                                    out_logits);

  // PQ gemm reads pre-bn h2p with bn2 fused into A-staging (no edot)
  dim3 gpq(2, (NN + 127) / 128);
  gemm_mfma<<<gpq, 256, 0, stream>>>(h2p, BPt, PQ, NN, HID, 256, sc2, sh2,
                                     nullptr, nullptr, nullptr, nullptr, 0);
  eimp_kernel<<<(EE + 15) / 16, 256, 0, stream>>>(csr_s, csr_d, csr_e, PQ,
                                                  ep_b1, ep_w2, ep_b2, out_imp);
}

// Round 14
// 590.148 us; speedup vs baseline: 1.0898x; 1.0898x over previous
//
#include <hip/hip_runtime.h>
#include <hip/hip_bf16.h>
#include <math.h>

typedef __hip_bfloat16 bf16;
typedef __bf16 bf16x8 __attribute__((ext_vector_type(8)));
typedef __bf16 bf16x2v __attribute__((ext_vector_type(2)));
typedef float f32x4 __attribute__((ext_vector_type(4)));

#define NN 50000
#define EE 400000
#define FIN 262
#define KP1 288   /* FIN padded to multiple of 32 */
#define HID 128
#define NH 4
#define C1 512   /* HID*NH */
#define NGR 16
#define SCAN_NB ((NN + 255) / 256)   /* 196 */

__device__ __forceinline__ float b2f(bf16 x){ return __bfloat162float(x); }
__device__ __forceinline__ bf16 f2b(float x){ return __float2bfloat16(x); }
__device__ __forceinline__ float lrelu(float v){ return v >= 0.f ? v : 0.2f * v; }
__device__ __forceinline__ float eluf(float v){ return v > 0.f ? v : expm1f(v); }

__global__ void zero_words(unsigned int* __restrict__ p, int n) {
  int i = blockIdx.x * 256 + threadIdx.x;
  if (i < n) p[i] = 0u;
}

// ================= MFMA GEMM: C(M,N) = A(M,K) @ B(K,N) =================
// Reg-staged double-buffered pipeline (1-deep lookahead — measured optimum);
// LDS 32 KiB, chunk-XOR swizzle on write+read. Optional fused bn (sc/sh) and
// per-row dual dot epilogue (es/ed; LDS-reduced, no atomics).
__global__ __launch_bounds__(256)
void gemm_mfma(const bf16* __restrict__ A, const bf16* __restrict__ Bt,
               bf16* __restrict__ C, int M, int K, int Ncols,
               const float* __restrict__ sc, const float* __restrict__ sh,
               const float* __restrict__ av, const float* __restrict__ bv,
               float* __restrict__ esp, float* __restrict__ edp, int dstride) {
  __shared__ __align__(16) __bf16 As[2][128 * 32];
  __shared__ __align__(16) __bf16 Bs[2][128 * 32];
  int bm = blockIdx.y * 128, bn = blockIdx.x * 128;
  int tid = threadIdx.x;
  int wave = tid >> 6, lane = tid & 63;
  int quad = lane >> 4, l16 = lane & 15;
  int wm = (wave >> 1) * 64, wn = (wave & 1) * 64;
  int rowA = (tid * 8) >> 5;          // 0..63 (each thread also covers rowA+64)
  int colT = (tid * 8) & 31;
  int swW = ((rowA >> 1) & 3) << 3;   // write-side chunk swizzle (same for rowA+64)
  int gm0 = bm + rowA, gm1 = bm + rowA + 64;
  int gn0 = bn + rowA, gn1 = bn + rowA + 64;
  const uint4 zz = {0u, 0u, 0u, 0u};

  f32x4 acc[4][4];
  #pragma unroll
  for (int i = 0; i < 4; ++i)
    #pragma unroll
    for (int j = 0; j < 4; ++j)
      acc[i][j] = (f32x4){0.f, 0.f, 0.f, 0.f};

  uint4 a0, a1, b0, b1;   // staging regs for the NEXT tile

  auto xf = [&](uint4 v, int kb) -> uint4 {   // kb = k0 + colT
    if (sc == nullptr) return v;
    bf16x8 a8 = *(bf16x8*)&v;
    float4 c0 = *(const float4*)(sc + kb);
    float4 c1 = *(const float4*)(sc + kb + 4);
    float4 h0 = *(const float4*)(sh + kb);
    float4 h1 = *(const float4*)(sh + kb + 4);
    bf16x8 t8;
    t8[0] = (__bf16)((float)a8[0] * c0.x + h0.x);
    t8[1] = (__bf16)((float)a8[1] * c0.y + h0.y);
    t8[2] = (__bf16)((float)a8[2] * c0.z + h0.z);
    t8[3] = (__bf16)((float)a8[3] * c0.w + h0.w);
    t8[4] = (__bf16)((float)a8[4] * c1.x + h1.x);
    t8[5] = (__bf16)((float)a8[5] * c1.y + h1.y);
    t8[6] = (__bf16)((float)a8[6] * c1.z + h1.z);
    t8[7] = (__bf16)((float)a8[7] * c1.w + h1.w);
    return *(uint4*)&t8;
  };
  auto ld = [&](int k0) {
    a0 = (gm0 < M) ? *(const uint4*)(A + (size_t)gm0 * K + k0 + colT) : zz;
    a1 = (gm1 < M) ? *(const uint4*)(A + (size_t)gm1 * K + k0 + colT) : zz;
    b0 = (gn0 < Ncols) ? *(const uint4*)(Bt + (size_t)gn0 * K + k0 + colT) : zz;
    b1 = (gn1 < Ncols) ? *(const uint4*)(Bt + (size_t)gn1 * K + k0 + colT) : zz;
  };
  auto st = [&](int buf, int k0) {
    int cw = colT ^ swW;
    *(uint4*)(&As[buf][rowA * 32 + cw])        = xf(a0, k0 + colT);
    *(uint4*)(&As[buf][(rowA + 64) * 32 + cw]) = xf(a1, k0 + colT);
    *(uint4*)(&Bs[buf][rowA * 32 + cw])        = b0;
    *(uint4*)(&Bs[buf][(rowA + 64) * 32 + cw]) = b1;
  };

  int nt = K >> 5;
  ld(0);
  st(0, 0);
  __syncthreads();

  for (int t = 0; t < nt; ++t) {
    int cur = t & 1;
    bool more = (t + 1 < nt);
    if (more) ld((t + 1) << 5);       // issue next-tile loads (no wait yet)

    bf16x8 af[4], bfr[4];
    #pragma unroll
    for (int i = 0; i < 4; ++i) {
      int r = wm + i * 16 + l16;
      af[i] = *(const bf16x8*)(&As[cur][r * 32 + ((quad << 3) ^ (((r >> 1) & 3) << 3))]);
    }
    #pragma unroll
    for (int j = 0; j < 4; ++j) {
      int r = wn + j * 16 + l16;
      bfr[j] = *(const bf16x8*)(&Bs[cur][r * 32 + ((quad << 3) ^ (((r >> 1) & 3) << 3))]);
    }
    #pragma unroll
    for (int i = 0; i < 4; ++i)
      #pragma unroll
      for (int j = 0; j < 4; ++j)
        acc[i][j] = __builtin_amdgcn_mfma_f32_16x16x32_bf16(af[i], bfr[j], acc[i][j], 0, 0, 0);

    if (more) st(cur ^ 1, (t + 1) << 5);  // vmcnt wait lands here, after MFMA issue
    __syncthreads();
  }

  // C write
  #pragma unroll
  for (int i = 0; i < 4; ++i) {
    #pragma unroll
    for (int r = 0; r < 4; ++r) {
      int gm = bm + wm + i * 16 + quad * 4 + r;
      if (gm >= M) continue;
      #pragma unroll
      for (int j = 0; j < 4; ++j) {
        int gn = bn + wn + j * 16 + l16;
        C[(size_t)gm * Ncols + gn] = f2b(acc[i][j][r]);
      }
    }
  }

  // fused edot epilogue: per-row dual dot over this block's 128 cols.
  // LDS reduction in dead As space; direct stores (no atomics).
  if (esp) {
    float* red = (float*)&As[0][0];   // 128 rows x {waveHalf} x {es,ed} = 2 KB
    float avj[4], bvj[4];
    #pragma unroll
    for (int j = 0; j < 4; ++j) {
      int gn = bn + wn + j * 16 + l16;
      avj[j] = av[gn]; bvj[j] = bv[gn];
    }
    #pragma unroll
    for (int i = 0; i < 4; ++i)
      #pragma unroll
      for (int r = 0; r < 4; ++r) {
        float pa = 0.f, pb = 0.f;
        #pragma unroll
        for (int j = 0; j < 4; ++j) {
          float v = acc[i][j][r];
          pa += v * avj[j]; pb += v * bvj[j];
        }
        #pragma unroll
        for (int off = 8; off > 0; off >>= 1) {
          pa += __shfl_xor(pa, off);
          pb += __shfl_xor(pb, off);
        }
        if (l16 == 0) {
          int rl = wm + i * 16 + quad * 4 + r;   // 0..127
          red[rl * 4 + (wave & 1) * 2 + 0] = pa;
          red[rl * 4 + (wave & 1) * 2 + 1] = pb;
        }
      }
    __syncthreads();
    if (tid < 128) {
      int gm = bm + tid;
      if (gm < M) {
        int hoff = (dstride == 4) ? (bn >> 7) : 0;
        esp[gm * dstride + hoff] = red[tid * 4 + 0] + red[tid * 4 + 2];
        edp[gm * dstride + hoff] = red[tid * 4 + 1] + red[tid * 4 + 3];
      }
    }
  }
}

// ---- merged prep: conv_x | b1t | b2t | bpt (range-dispatched) ----
#define PR0 (NN * KP1)                 /* 14,400,000 */
#define PR1 (PR0 + C1 * KP1)           /* 14,547,456 */
#define PR2 (PR1 + HID * C1)           /* 14,612,992 */
#define PR3 (PR2 + 256 * HID)          /* 14,645,760 */
__global__ void prep_all(const float* __restrict__ x, const float* __restrict__ W1,
                         const float* __restrict__ W2, const float* __restrict__ epw1,
                         bf16* __restrict__ xb, bf16* __restrict__ B1t,
                         bf16* __restrict__ B2t, bf16* __restrict__ BPt) {
  int i = blockIdx.x * 256 + threadIdx.x;
  if (i < PR0) {
    int row = i / KP1, col = i - row * KP1;
    xb[i] = (col < FIN) ? f2b(x[(size_t)row * FIN + col]) : f2b(0.f);
  } else if (i < PR1) {
    int j = i - PR0;
    int n = j / KP1, k = j - n * KP1;   // n = h*128 + o
    int h = n >> 7, o = n & 127;
    B1t[j] = (k < FIN) ? f2b(W1[((size_t)h * FIN + k) * HID + o]) : f2b(0.f);
  } else if (i < PR2) {
    int j = i - PR1;
    int n = j >> 9, k = j & 511;
    B2t[j] = f2b(W2[(size_t)k * HID + n]);
  } else if (i < PR3) {
    int j = i - PR2;
    int n = j >> 7, k = j & 127;
    float v = (n < 128) ? epw1[(size_t)k * HID + n]
                        : epw1[(size_t)(128 + k) * HID + (n - 128)];
    BPt[j] = f2b(v);
  }
}

// ---------------- CSR build ----------------
__global__ void count_kernel(const int* __restrict__ dst, int* __restrict__ deg, int E) {
  int e = blockIdx.x * blockDim.x + threadIdx.x;
  if (e >= E) return;
  int d = dst[e];
  if ((unsigned)d < NN) atomicAdd(&deg[d], 1);
}

__global__ void scan_p1(const int* __restrict__ deg, int* __restrict__ bsum) {
  __shared__ int s[256];
  int t = threadIdx.x;
  int i = blockIdx.x * 256 + t;
  s[t] = (i < NN) ? deg[i] : 0;
  __syncthreads();
  #pragma unroll
  for (int off = 128; off > 0; off >>= 1) {
    if (t < off) s[t] += s[t + off];
    __syncthreads();
  }
  if (t == 0) bsum[blockIdx.x] = s[0];
}
// parallel Hillis-Steele exclusive scan over block sums
__global__ void scan_p2(const int* __restrict__ bsum, int* __restrict__ boff,
                        int* __restrict__ total_out) {
  __shared__ int s[256];
  int t = threadIdx.x;
  int v = (t < SCAN_NB) ? bsum[t] : 0;
  s[t] = v;
  __syncthreads();
  #pragma unroll
  for (int off = 1; off < 256; off <<= 1) {
    int add = (t >= off) ? s[t - off] : 0;
    __syncthreads();
    s[t] += add;
    __syncthreads();
  }
  if (t < SCAN_NB) boff[t] = s[t] - v;   // exclusive
  if (t == 255) total_out[0] = s[255];   // rowptr[NN]
}
__global__ void scan_p3(const int* __restrict__ deg, const int* __restrict__ boff,
                        int* __restrict__ rowptr, int* __restrict__ cursor) {
  __shared__ int s[256];
  int t = threadIdx.x;
  int i = blockIdx.x * 256 + t;
  int v = (i < NN) ? deg[i] : 0;
  s[t] = v;
  __syncthreads();
  #pragma unroll
  for (int off = 1; off < 256; off <<= 1) {
    int add = (t >= off) ? s[t - off] : 0;
    __syncthreads();
    s[t] += add;
    __syncthreads();
  }
  if (i < NN) {
    int pos = boff[blockIdx.x] + s[t] - v;   // exclusive
    rowptr[i] = pos;
    cursor[i] = pos;
  }
}

__global__ void scatter_kernel(const int* __restrict__ src, const int* __restrict__ dst,
                               int* __restrict__ cursor, int* __restrict__ csr_s,
                               int* __restrict__ csr_d, int* __restrict__ csr_e, int E) {
  int e = blockIdx.x * blockDim.x + threadIdx.x;
  if (e >= E) return;
  int d = dst[e];
  if ((unsigned)d >= NN) return;
  int s = src[e]; if ((unsigned)s >= NN) s = 0;
  int p = atomicAdd(&cursor[d], 1);
  if ((unsigned)p < (unsigned)E) { csr_s[p] = s; csr_d[p] = d; csr_e[p] = e; }
}

// ---- layer-1 aggregate: wave per node, 8/4/1 tiered loop, logits inline (no max-sub) ----
// exp(v)/sum(exp(v)) == exp(v-m)/sum(exp(v-m)); epsilon rel-diff <= 1e-8
__global__ __launch_bounds__(256, 6)
void agg1_all(const int* __restrict__ csr_s, const int* __restrict__ rowptr,
              const float* __restrict__ es, const float* __restrict__ ed,
              const bf16* __restrict__ Wh1, bf16* __restrict__ h1) {
  int wid = threadIdx.x >> 6, lane = threadIdx.x & 63;
  int node = blockIdx.x * 4 + wid;
  if (node >= NN) return;
  int b = rowptr[node], e = rowptr[node + 1];
  if (b < 0) b = 0; if (e > EE) e = EE;
  int h = lane >> 4;
  float edh = ed[node * 4 + h];
  float sum = 0.f;
  float acc[8] = {};
  const bf16* W = Wh1 + lane * 8;
  int j = b;
  for (; j + 8 <= e; j += 8) {
    int s_[8];
    #pragma unroll
    for (int i = 0; i < 8; ++i) s_[i] = csr_s[j + i];
    float w[8];
    bf16x8 r[8];
    #pragma unroll
    for (int i = 0; i < 8; ++i) {
      w[i] = es[s_[i] * 4 + h];
      r[i] = *(const bf16x8*)(W + (size_t)s_[i] * C1);
    }
    #pragma unroll
    for (int i = 0; i < 8; ++i) {
      float p = __expf(lrelu(w[i] + edh));
      sum += p;
      #pragma unroll
      for (int k = 0; k < 8; ++k) acc[k] += p * (float)r[i][k];
    }
  }
  if (j + 4 <= e) {
    int s_[4];
    #pragma unroll
    for (int i = 0; i < 4; ++i) s_[i] = csr_s[j + i];
    float w[4];
    bf16x8 r[4];
    #pragma unroll
    for (int i = 0; i < 4; ++i) {
      w[i] = es[s_[i] * 4 + h];
      r[i] = *(const bf16x8*)(W + (size_t)s_[i] * C1);
    }
    #pragma unroll
    for (int i = 0; i < 4; ++i) {
      float p = __expf(lrelu(w[i] + edh));
      sum += p;
      #pragma unroll
      for (int k = 0; k < 8; ++k) acc[k] += p * (float)r[i][k];
    }
    j += 4;
  }
  for (; j < e; ++j) {
    int s0 = csr_s[j];
    float p = __expf(lrelu(es[s0 * 4 + h] + edh));
    bf16x8 r0 = *(const bf16x8*)(W + (size_t)s0 * C1);
    sum += p;
    #pragma unroll
    for (int k = 0; k < 8; ++k) acc[k] += p * (float)r0[k];
  }
  float scale = 1.f / (sum + 1e-8f);
  bf16x8 o;
  #pragma unroll
  for (int k = 0; k < 8; ++k) o[k] = (__bf16)eluf(acc[k] * scale);
  *(bf16x8*)(h1 + (size_t)node * C1 + lane * 8) = o;
}

// ---- layer-2 aggregate (H=1): 16-lane group per node, logits inline;
//      attention output fused (lane-parallel pass over the node's edges) ----
__global__ __launch_bounds__(256, 8)
void agg2_all(const int* __restrict__ csr_s, const int* __restrict__ csr_e,
              const int* __restrict__ rowptr,
              const float* __restrict__ es, const float* __restrict__ ed,
              const bf16* __restrict__ Wh2, bf16* __restrict__ h2p,
              float* __restrict__ out_attn) {
  int tid = threadIdx.x;
  int l16 = tid & 15;
  int node = blockIdx.x * 16 + (tid >> 4);
  if (node >= NN) return;
  int b = rowptr[node], e = rowptr[node + 1];
  if (b < 0) b = 0; if (e > EE) e = EE;
  float edn = ed[node];
  float sum = 0.f;
  float acc[8] = {};
  const bf16* W = Wh2 + l16 * 8;
  int j = b;
  for (; j + 4 <= e; j += 4) {
    int s_[4];
    #pragma unroll
    for (int i = 0; i < 4; ++i) s_[i] = csr_s[j + i];
    float w[4];
    bf16x8 r[4];
    #pragma unroll
    for (int i = 0; i < 4; ++i) {
      w[i] = es[s_[i]];
      r[i] = *(const bf16x8*)(W + (size_t)s_[i] * HID);
    }
    #pragma unroll
    for (int i = 0; i < 4; ++i) {
      float p = __expf(lrelu(w[i] + edn));
      sum += p;
      #pragma unroll
      for (int k = 0; k < 8; ++k) acc[k] += p * (float)r[i][k];
    }
  }
  for (; j < e; ++j) {
    int s0 = csr_s[j];
    float p = __expf(lrelu(es[s0] + edn));
    bf16x8 r0 = *(const bf16x8*)(W + (size_t)s0 * HID);
    sum += p;
    #pragma unroll
    for (int k = 0; k < 8; ++k) acc[k] += p * (float)r0[k];
  }
  float scale = 1.f / (sum + 1e-8f);
  bf16x8 o;
  #pragma unroll
  for (int k = 0; k < 8; ++k) o[k] = (__bf16)eluf(acc[k] * scale);
  *(bf16x8*)(h2p + (size_t)node * HID + l16 * 8) = o;
  for (int t = b + l16; t < e; t += 16) {
    int s0 = csr_s[t];
    int eid = csr_e[t];
    float p = __expf(lrelu(es[s0] + edn));
    if ((unsigned)eid < EE) out_attn[eid] = p * scale;
  }
}

// ---- read-only per-column stats: blockDim == C, thread-per-column ----
__global__ void stats_ro(const bf16* __restrict__ X, float* __restrict__ cs,
                         float* __restrict__ cq, int Nrows, int C) {
  int c = threadIdx.x;
  int rpb = (Nrows + gridDim.x - 1) / gridDim.x;
  int r0 = blockIdx.x * rpb, r1 = min(r0 + rpb, Nrows);
  float s = 0.f, s2 = 0.f;
  for (int r = r0; r < r1; ++r) {
    float v = b2f(X[(size_t)r * C + c]);
    s += v; s2 += v * v;
  }
  atomicAdd(&cs[c], s);
  atomicAdd(&cq[c], s2);
}

// ---- bn coefficients: sc = gamma*rstd, sh = beta - mu*gamma*rstd ----
__global__ void bn_coef(const float* __restrict__ cs, const float* __restrict__ cq,
                        const float* __restrict__ gamma, const float* __restrict__ beta,
                        float* __restrict__ sc, float* __restrict__ sh, int C, float invN) {
  int c = blockIdx.x * 256 + threadIdx.x;
  if (c >= C) return;
  float mu = cs[c] * invN;
  float var = cq[c] * invN - mu * mu;
  float g = rsqrtf(fmaxf(var, 0.f) + 1e-5f) * gamma[c];
  sc[c] = g;
  sh[c] = beta[c] - mu * g;
}

// ---- fused bn-apply (f32 out) + global mean pool (post-bn sums) ----
__global__ __launch_bounds__(256)
void poolbn_kernel(const bf16* __restrict__ h2p, const int* __restrict__ batch,
                   const float* __restrict__ sc, const float* __restrict__ sh,
                   float* __restrict__ out_h2, float* __restrict__ pooled) {
  int t = threadIdx.x;
  int f = t & 127, half = t >> 7;
  float scf = sc[f], shf = sh[f];
  int r0 = blockIdx.x * 32;
  int g_cur = -1;
  float acc = 0.f;
  #pragma unroll
  for (int i = 0; i < 16; ++i) {
    int r = r0 + half + 2 * i;
    if (r >= NN) break;
    int g = batch[r]; if ((unsigned)g >= NGR) g = 0;
    float v = b2f(h2p[(size_t)r * HID + f]) * scf + shf;
    out_h2[(size_t)r * HID + f] = v;
    if (g != g_cur) {
      if (g_cur >= 0) atomicAdd(&pooled[g_cur * HID + f], acc);
      g_cur = g; acc = 0.f;
    }
    acc += v;
  }
  if (g_cur >= 0) atomicAdd(&pooled[g_cur * HID + f], acc);
}

// ---- classifier (tiny, single block); counts computed in-kernel ----
__global__ void cls_kernel(const float* __restrict__ pooled, const int* __restrict__ batch,
                           const float* __restrict__ w1, const float* __restrict__ b1,
                           const float* __restrict__ w2, const float* __restrict__ b2,
                           float* __restrict__ out) {
  __shared__ float repr[NGR * HID];
  __shared__ float hid[NGR * 64];
  __shared__ float scnt[NGR];
  int t = threadIdx.x;  // 128
  if (t < NGR) {
    int g = t;
    int a = 0, b = NN;
    while (a < b) { int m = (a + b) >> 1; if (batch[m] < g) a = m + 1; else b = m; }
    int lb = a;
    a = 0; b = NN;
    while (a < b) { int m = (a + b) >> 1; if (batch[m] <= g) a = m + 1; else b = m; }
    scnt[t] = (float)(a - lb);
  }
  __syncthreads();
  for (int i = t; i < NGR * HID; i += 128) {
    int g = i >> 7;
    repr[i] = pooled[i] / fmaxf(scnt[g], 1.f);
  }
  __syncthreads();
  for (int i = t; i < NGR * 64; i += 128) {
    int g = i >> 6, j = i & 63;
    float s = b1[j];
    for (int c = 0; c < HID; ++c) s += repr[g * HID + c] * w1[c * 64 + j];
    hid[i] = fmaxf(s, 0.f);
  }
  __syncthreads();
  if (t < NGR * 2) {
    int g = t >> 1, k = t & 1;
    float s = b2[k];
    for (int j = 0; j < 64; ++j) s += hid[g * 64 + j] * w2[j * 2 + k];
    out[t] = s;
  }
}

// ---- edge importance from fused PQ (N,256): CSR order, 16-lane group per edge ----
__global__ __launch_bounds__(256)
void eimp_kernel(const int* __restrict__ csr_s, const int* __restrict__ csr_d,
                 const int* __restrict__ csr_e, const bf16* __restrict__ PQ,
                 const float* __restrict__ b1, const float* __restrict__ w2,
                 const float* __restrict__ b2, float* __restrict__ out) {
  int tid = threadIdx.x;
  int wave = tid >> 6, lane = tid & 63;
  int g = lane >> 4, l16 = lane & 15;
  int slot = blockIdx.x * 16 + wave * 4 + g;
  if (slot >= EE) return;
  int s = csr_s[slot]; if ((unsigned)s >= NN) s = 0;
  int d = csr_d[slot]; if ((unsigned)d >= NN) d = 0;
  int e = csr_e[slot]; if ((unsigned)e >= EE) return;
  bf16x8 p = *(const bf16x8*)(PQ + (size_t)s * 256 + l16 * 8);
  bf16x8 q = *(const bf16x8*)(PQ + (size_t)d * 256 + 128 + l16 * 8);
  float acc = 0.f;
  #pragma unroll
  for (int r = 0; r < 8; ++r) {
    int jj = l16 * 8 + r;
    float hh = (float)p[r] + (float)q[r] + b1[jj];
    hh = fmaxf(hh, 0.f);
    acc += hh * w2[jj];
  }
  #pragma unroll
  for (int off = 8; off > 0; off >>= 1) acc += __shfl_xor(acc, off);
  if (l16 == 0) {
    float z = acc + b2[0];
    out[e] = 1.f / (1.f + expf(-z));
  }
}

extern "C" void kernel_launch(void* const* d_in, const int* in_sizes, int n_in,
                              void* d_out, int out_size, void* d_ws, size_t ws_size,
                              hipStream_t stream) {
  const float* x      = (const float*)d_in[0];
  const int*   ei     = (const int*)d_in[1];
  const int*   batch  = (const int*)d_in[2];
  const float* W1     = (const float*)d_in[3];
  const float* a_src1 = (const float*)d_in[4];
  const float* a_dst1 = (const float*)d_in[5];
  const float* W2     = (const float*)d_in[6];
  const float* a_src2 = (const float*)d_in[7];
  const float* a_dst2 = (const float*)d_in[8];
  const float* bn1_g  = (const float*)d_in[9];
  const float* bn1_b  = (const float*)d_in[10];
  const float* bn2_g  = (const float*)d_in[11];
  const float* bn2_b  = (const float*)d_in[12];
  const float* cls_w1 = (const float*)d_in[13];
  const float* cls_b1 = (const float*)d_in[14];
  const float* cls_w2 = (const float*)d_in[15];
  const float* cls_b2 = (const float*)d_in[16];
  const float* ep_w1  = (const float*)d_in[17];
  const float* ep_b1  = (const float*)d_in[18];
  const float* ep_w2  = (const float*)d_in[19];
  const float* ep_b2  = (const float*)d_in[20];

  const int* srcp = ei;
  const int* dstp = ei + EE;

  // ---- workspace layout (bytes), peak ~110.5 MB, hazard-checked ----
  char* base = (char*)d_ws;
  bf16* xb   = (bf16*)(base);
  bf16* h1   = (bf16*)(base);
  bf16* Wh1  = (bf16*)(base + 51200000);
  bf16* Wh2  = (bf16*)(base + 51200000);
  bf16* PQ   = (bf16*)(base + 51200000);
  bf16* h2p  = (bf16*)(base + 76800000);
  float* es1   = (float*)(base + 102400000);    // (N,4) fully written by gemm1 epilogue
  float* ed1   = (float*)(base + 103200000);    // (N,4)
  float* es2   = (float*)(base + 104000000);    // (N)
  float* ed2   = (float*)(base + 104200000);    // (N)
  int*   deg   = (int*)(base + 104400000);      // (N)   [zero region start]
  float* stats = (float*)(base + 104600000);    // 3344 floats -> end 104,613,376
  float* cs1 = stats,        *cq1 = stats + 512;
  float* cs2 = stats + 1024, *cq2 = stats + 1152;
  float* pooled = stats + 1280;                 // 16*128
  float* sc1   = (float*)(base + 104613376);    // (512)
  float* sh1   = (float*)(base + 104615424);    // (512)
  float* sc2   = (float*)(base + 104617472);    // (128)
  float* sh2   = (float*)(base + 104617984);    // (128) -> 104,618,496
  int*   cursor= (int*)(base + 104818496);      // (N)
  int*   rowptr= (int*)(base + 105018496);      // (N+1) -> 105,218,500
  int*   bsum  = (int*)(base + 105218560);      // 256 + 256
  int*   boff  = bsum + 256;
  int*   csr_s = (int*)(base + 105220608);      // (E)
  int*   csr_d = (int*)(base + 106820608);      // (E)
  int*   csr_e = (int*)(base + 108420608);      // (E)
  bf16*  B1t   = (bf16*)(base + 110020608);     // (512,288)
  bf16*  B2t   = (bf16*)(base + 110315520);     // (128,512)
  bf16*  BPt   = (bf16*)(base + 110446592);     // (256,128) -> ends 110,512,128

  float* out        = (float*)d_out;
  float* out_logits = out;                          // 32
  float* out_h2     = out + 32;                     // N*128
  float* out_imp    = out + 32 + (size_t)NN * HID;  // E
  float* out_attn   = out_imp + EE;                 // E

  // zero deg+stats in one call (contiguous; 213,376 B = 53,344 words)
  zero_words<<<(53344 + 255) / 256, 256, 0, stream>>>((unsigned int*)deg, 53344);

  // merged prep: bf16 conversions / transposes
  prep_all<<<(PR3 + 255) / 256, 256, 0, stream>>>(x, W1, W2, ep_w1, xb, B1t, B2t, BPt);

  // CSR by destination; parallel 3-phase scan
  count_kernel<<<(EE + 255) / 256, 256, 0, stream>>>(dstp, deg, EE);
  scan_p1<<<SCAN_NB, 256, 0, stream>>>(deg, bsum);
  scan_p2<<<1, 256, 0, stream>>>(bsum, boff, rowptr + NN);
  scan_p3<<<SCAN_NB, 256, 0, stream>>>(deg, boff, rowptr, cursor);
  scatter_kernel<<<(EE + 255) / 256, 256, 0, stream>>>(srcp, dstp, cursor,
                                                       csr_s, csr_d, csr_e, EE);

  // ---- layer 1: GEMM (edot fused via LDS, no atomics) + aggregate ----
  dim3 g1(C1 / 128, (NN + 127) / 128);
  gemm_mfma<<<g1, 256, 0, stream>>>(xb, B1t, Wh1, NN, KP1, C1, nullptr, nullptr,
                                    a_src1, a_dst1, es1, ed1, 4);
  agg1_all<<<(NN + 3) / 4, 256, 0, stream>>>(csr_s, rowptr, es1, ed1, Wh1, h1);

  // read-only stats on ELU'd h1; bn folded into gemm2's A-staging
  stats_ro<<<400, C1, 0, stream>>>(h1, cs1, cq1, NN, C1);
  bn_coef<<<2, 256, 0, stream>>>(cs1, cq1, bn1_g, bn1_b, sc1, sh1, C1, 1.f / NN);

  // ---- layer 2 (edot fused into gemm2; attn output fused into agg2) ----
  dim3 g2(1, (NN + 127) / 128);
  gemm_mfma<<<g2, 256, 0, stream>>>(h1, B2t, Wh2, NN, C1, HID, sc1, sh1,
                                    a_src2, a_dst2, es2, ed2, 1);
  agg2_all<<<(NN + 15) / 16, 256, 0, stream>>>(csr_s, csr_e, rowptr, es2, ed2,
                                               Wh2, h2p, out_attn);

  stats_ro<<<400, HID, 0, stream>>>(h2p, cs2, cq2, NN, HID);
  bn_coef<<<1, 256, 0, stream>>>(cs2, cq2, bn2_g, bn2_b, sc2, sh2, HID, 1.f / NN);

  // fused bn-out + pool (post-bn sums), then classifier (counts in-kernel)
  poolbn_kernel<<<(NN + 31) / 32, 256, 0, stream>>>(h2p, batch, sc2, sh2, out_h2, pooled);
  cls_kernel<<<1, 128, 0, stream>>>(pooled, batch, cls_w1, cls_b1, cls_w2, cls_b2,
                                    out_logits);

  // PQ gemm reads pre-bn h2p with bn2 fused into A-staging (no edot)
  dim3 gpq(2, (NN + 127) / 128);
  gemm_mfma<<<gpq, 256, 0, stream>>>(h2p, BPt, PQ, NN, HID, 256, sc2, sh2,
                                     nullptr, nullptr, nullptr, nullptr, 0);
  eimp_kernel<<<(EE + 15) / 16, 256, 0, stream>>>(csr_s, csr_d, csr_e, PQ,
                                                  ep_b1, ep_w2, ep_b2, out_imp);
}

// Round 15
// 587.512 us; speedup vs baseline: 1.0947x; 1.0045x over previous
//
#include <hip/hip_runtime.h>
#include <hip/hip_bf16.h>
#include <math.h>

typedef __hip_bfloat16 bf16;
typedef __bf16 bf16x8 __attribute__((ext_vector_type(8)));
typedef __bf16 bf16x2v __attribute__((ext_vector_type(2)));
typedef float f32x4 __attribute__((ext_vector_type(4)));

#define NN 50000
#define EE 400000
#define FIN 262
#define KP1 288   /* FIN padded to multiple of 32 */
#define HID 128
#define NH 4
#define C1 512   /* HID*NH */
#define NGR 16
#define SCAN_NB ((NN + 255) / 256)   /* 196 */

__device__ __forceinline__ float b2f(bf16 x){ return __bfloat162float(x); }
__device__ __forceinline__ bf16 f2b(float x){ return __float2bfloat16(x); }
__device__ __forceinline__ float lrelu(float v){ return v >= 0.f ? v : 0.2f * v; }
__device__ __forceinline__ float eluf(float v){ return v > 0.f ? v : expm1f(v); }

__global__ void zero_words(unsigned int* __restrict__ p, int n) {
  int i = blockIdx.x * 256 + threadIdx.x;
  if (i < n) p[i] = 0u;
}

// ================= MFMA GEMM: C(M,N) = A(M,K) @ B(K,N) =================
// Reg-staged double-buffered pipeline (1-deep lookahead — measured optimum);
// LDS 32 KiB, chunk-XOR swizzle on write+read. Optional fused bn (sc/sh) and
// per-row dual dot epilogue (es/ed; LDS-reduced, no atomics).
// XCD-aware 1D grid: each XCD owns a contiguous chunk of row-panels with its
// col-blocks adjacent -> A-panel slice (3.6MB) L2-resident per XCD.
// grid = 8 * g8 * nbx, g8 = ceil(nby/8); pad blocks exit before any barrier.
__global__ __launch_bounds__(256)
void gemm_mfma(const bf16* __restrict__ A, const bf16* __restrict__ Bt,
               bf16* __restrict__ C, int M, int K, int Ncols,
               int nbxShift, int nby, int g8,
               const float* __restrict__ sc, const float* __restrict__ sh,
               const float* __restrict__ av, const float* __restrict__ bv,
               float* __restrict__ esp, float* __restrict__ edp, int dstride) {
  __shared__ __align__(16) __bf16 As[2][128 * 32];
  __shared__ __align__(16) __bf16 Bs[2][128 * 32];
  int s = blockIdx.x;
  int xcd = s & 7;
  int j = s >> 3;
  int by = xcd * g8 + (j >> nbxShift);
  int bx = j & ((1 << nbxShift) - 1);
  if (by >= nby) return;              // uniform exit, before any barrier
  int bm = by * 128, bn = bx * 128;
  int tid = threadIdx.x;
  int wave = tid >> 6, lane = tid & 63;
  int quad = lane >> 4, l16 = lane & 15;
  int wm = (wave >> 1) * 64, wn = (wave & 1) * 64;
  int rowA = (tid * 8) >> 5;          // 0..63 (each thread also covers rowA+64)
  int colT = (tid * 8) & 31;
  int swW = ((rowA >> 1) & 3) << 3;   // write-side chunk swizzle (same for rowA+64)
  int gm0 = bm + rowA, gm1 = bm + rowA + 64;
  int gn0 = bn + rowA, gn1 = bn + rowA + 64;
  const uint4 zz = {0u, 0u, 0u, 0u};

  f32x4 acc[4][4];
  #pragma unroll
  for (int i = 0; i < 4; ++i)
    #pragma unroll
    for (int jj = 0; jj < 4; ++jj)
      acc[i][jj] = (f32x4){0.f, 0.f, 0.f, 0.f};

  uint4 a0, a1, b0, b1;   // staging regs for the NEXT tile

  auto xf = [&](uint4 v, int kb) -> uint4 {   // kb = k0 + colT
    if (sc == nullptr) return v;
    bf16x8 a8 = *(bf16x8*)&v;
    float4 c0 = *(const float4*)(sc + kb);
    float4 c1 = *(const float4*)(sc + kb + 4);
    float4 h0 = *(const float4*)(sh + kb);
    float4 h1 = *(const float4*)(sh + kb + 4);
    bf16x8 t8;
    t8[0] = (__bf16)((float)a8[0] * c0.x + h0.x);
    t8[1] = (__bf16)((float)a8[1] * c0.y + h0.y);
    t8[2] = (__bf16)((float)a8[2] * c0.z + h0.z);
    t8[3] = (__bf16)((float)a8[3] * c0.w + h0.w);
    t8[4] = (__bf16)((float)a8[4] * c1.x + h1.x);
    t8[5] = (__bf16)((float)a8[5] * c1.y + h1.y);
    t8[6] = (__bf16)((float)a8[6] * c1.z + h1.z);
    t8[7] = (__bf16)((float)a8[7] * c1.w + h1.w);
    return *(uint4*)&t8;
  };
  auto ld = [&](int k0) {
    a0 = (gm0 < M) ? *(const uint4*)(A + (size_t)gm0 * K + k0 + colT) : zz;
    a1 = (gm1 < M) ? *(const uint4*)(A + (size_t)gm1 * K + k0 + colT) : zz;
    b0 = (gn0 < Ncols) ? *(const uint4*)(Bt + (size_t)gn0 * K + k0 + colT) : zz;
    b1 = (gn1 < Ncols) ? *(const uint4*)(Bt + (size_t)gn1 * K + k0 + colT) : zz;
  };
  auto st = [&](int buf, int k0) {
    int cw = colT ^ swW;
    *(uint4*)(&As[buf][rowA * 32 + cw])        = xf(a0, k0 + colT);
    *(uint4*)(&As[buf][(rowA + 64) * 32 + cw]) = xf(a1, k0 + colT);
    *(uint4*)(&Bs[buf][rowA * 32 + cw])        = b0;
    *(uint4*)(&Bs[buf][(rowA + 64) * 32 + cw]) = b1;
  };

  int nt = K >> 5;
  ld(0);
  st(0, 0);
  __syncthreads();

  for (int t = 0; t < nt; ++t) {
    int cur = t & 1;
    bool more = (t + 1 < nt);
    if (more) ld((t + 1) << 5);       // issue next-tile loads (no wait yet)

    bf16x8 af[4], bfr[4];
    #pragma unroll
    for (int i = 0; i < 4; ++i) {
      int r = wm + i * 16 + l16;
      af[i] = *(const bf16x8*)(&As[cur][r * 32 + ((quad << 3) ^ (((r >> 1) & 3) << 3))]);
    }
    #pragma unroll
    for (int jj = 0; jj < 4; ++jj) {
      int r = wn + jj * 16 + l16;
      bfr[jj] = *(const bf16x8*)(&Bs[cur][r * 32 + ((quad << 3) ^ (((r >> 1) & 3) << 3))]);
    }
    #pragma unroll
    for (int i = 0; i < 4; ++i)
      #pragma unroll
      for (int jj = 0; jj < 4; ++jj)
        acc[i][jj] = __builtin_amdgcn_mfma_f32_16x16x32_bf16(af[i], bfr[jj], acc[i][jj], 0, 0, 0);

    if (more) st(cur ^ 1, (t + 1) << 5);  // vmcnt wait lands here, after MFMA issue
    __syncthreads();
  }

  // C write
  #pragma unroll
  for (int i = 0; i < 4; ++i) {
    #pragma unroll
    for (int r = 0; r < 4; ++r) {
      int gm = bm + wm + i * 16 + quad * 4 + r;
      if (gm >= M) continue;
      #pragma unroll
      for (int jj = 0; jj < 4; ++jj) {
        int gn = bn + wn + jj * 16 + l16;
        C[(size_t)gm * Ncols + gn] = f2b(acc[i][jj][r]);
      }
    }
  }

  // fused edot epilogue: per-row dual dot over this block's 128 cols.
  // LDS reduction in dead As space; direct stores (no atomics).
  if (esp) {
    float* red = (float*)&As[0][0];   // 128 rows x {waveHalf} x {es,ed} = 2 KB
    float avj[4], bvj[4];
    #pragma unroll
    for (int jj = 0; jj < 4; ++jj) {
      int gn = bn + wn + jj * 16 + l16;
      avj[jj] = av[gn]; bvj[jj] = bv[gn];
    }
    #pragma unroll
    for (int i = 0; i < 4; ++i)
      #pragma unroll
      for (int r = 0; r < 4; ++r) {
        float pa = 0.f, pb = 0.f;
        #pragma unroll
        for (int jj = 0; jj < 4; ++jj) {
          float v = acc[i][jj][r];
          pa += v * avj[jj]; pb += v * bvj[jj];
        }
        #pragma unroll
        for (int off = 8; off > 0; off >>= 1) {
          pa += __shfl_xor(pa, off);
          pb += __shfl_xor(pb, off);
        }
        if (l16 == 0) {
          int rl = wm + i * 16 + quad * 4 + r;   // 0..127
          red[rl * 4 + (wave & 1) * 2 + 0] = pa;
          red[rl * 4 + (wave & 1) * 2 + 1] = pb;
        }
      }
    __syncthreads();
    if (tid < 128) {
      int gm = bm + tid;
      if (gm < M) {
        int hoff = (dstride == 4) ? (bn >> 7) : 0;
        esp[gm * dstride + hoff] = red[tid * 4 + 0] + red[tid * 4 + 2];
        edp[gm * dstride + hoff] = red[tid * 4 + 1] + red[tid * 4 + 3];
      }
    }
  }
}

// ---- merged prep: conv_x | b1t | b2t | bpt (range-dispatched) ----
#define PR0 (NN * KP1)                 /* 14,400,000 */
#define PR1 (PR0 + C1 * KP1)           /* 14,547,456 */
#define PR2 (PR1 + HID * C1)           /* 14,612,992 */
#define PR3 (PR2 + 256 * HID)          /* 14,645,760 */
__global__ void prep_all(const float* __restrict__ x, const float* __restrict__ W1,
                         const float* __restrict__ W2, const float* __restrict__ epw1,
                         bf16* __restrict__ xb, bf16* __restrict__ B1t,
                         bf16* __restrict__ B2t, bf16* __restrict__ BPt) {
  int i = blockIdx.x * 256 + threadIdx.x;
  if (i < PR0) {
    int row = i / KP1, col = i - row * KP1;
    xb[i] = (col < FIN) ? f2b(x[(size_t)row * FIN + col]) : f2b(0.f);
  } else if (i < PR1) {
    int j = i - PR0;
    int n = j / KP1, k = j - n * KP1;   // n = h*128 + o
    int h = n >> 7, o = n & 127;
    B1t[j] = (k < FIN) ? f2b(W1[((size_t)h * FIN + k) * HID + o]) : f2b(0.f);
  } else if (i < PR2) {
    int j = i - PR1;
    int n = j >> 9, k = j & 511;
    B2t[j] = f2b(W2[(size_t)k * HID + n]);
  } else if (i < PR3) {
    int j = i - PR2;
    int n = j >> 7, k = j & 127;
    float v = (n < 128) ? epw1[(size_t)k * HID + n]
                        : epw1[(size_t)(128 + k) * HID + (n - 128)];
    BPt[j] = f2b(v);
  }
}

// ---------------- CSR build ----------------
__global__ void count_kernel(const int* __restrict__ dst, int* __restrict__ deg, int E) {
  int e = blockIdx.x * blockDim.x + threadIdx.x;
  if (e >= E) return;
  int d = dst[e];
  if ((unsigned)d < NN) atomicAdd(&deg[d], 1);
}

__global__ void scan_p1(const int* __restrict__ deg, int* __restrict__ bsum) {
  __shared__ int s[256];
  int t = threadIdx.x;
  int i = blockIdx.x * 256 + t;
  s[t] = (i < NN) ? deg[i] : 0;
  __syncthreads();
  #pragma unroll
  for (int off = 128; off > 0; off >>= 1) {
    if (t < off) s[t] += s[t + off];
    __syncthreads();
  }
  if (t == 0) bsum[blockIdx.x] = s[0];
}
// parallel Hillis-Steele exclusive scan over block sums
__global__ void scan_p2(const int* __restrict__ bsum, int* __restrict__ boff,
                        int* __restrict__ total_out) {
  __shared__ int s[256];
  int t = threadIdx.x;
  int v = (t < SCAN_NB) ? bsum[t] : 0;
  s[t] = v;
  __syncthreads();
  #pragma unroll
  for (int off = 1; off < 256; off <<= 1) {
    int add = (t >= off) ? s[t - off] : 0;
    __syncthreads();
    s[t] += add;
    __syncthreads();
  }
  if (t < SCAN_NB) boff[t] = s[t] - v;   // exclusive
  if (t == 255) total_out[0] = s[255];   // rowptr[NN]
}
__global__ void scan_p3(const int* __restrict__ deg, const int* __restrict__ boff,
                        int* __restrict__ rowptr, int* __restrict__ cursor) {
  __shared__ int s[256];
  int t = threadIdx.x;
  int i = blockIdx.x * 256 + t;
  int v = (i < NN) ? deg[i] : 0;
  s[t] = v;
  __syncthreads();
  #pragma unroll
  for (int off = 1; off < 256; off <<= 1) {
    int add = (t >= off) ? s[t - off] : 0;
    __syncthreads();
    s[t] += add;
    __syncthreads();
  }
  if (i < NN) {
    int pos = boff[blockIdx.x] + s[t] - v;   // exclusive
    rowptr[i] = pos;
    cursor[i] = pos;
  }
}

__global__ void scatter_kernel(const int* __restrict__ src, const int* __restrict__ dst,
                               int* __restrict__ cursor, int* __restrict__ csr_s,
                               int* __restrict__ csr_d, int* __restrict__ csr_e, int E) {
  int e = blockIdx.x * blockDim.x + threadIdx.x;
  if (e >= E) return;
  int d = dst[e];
  if ((unsigned)d >= NN) return;
  int s = src[e]; if ((unsigned)s >= NN) s = 0;
  int p = atomicAdd(&cursor[d], 1);
  if ((unsigned)p < (unsigned)E) { csr_s[p] = s; csr_d[p] = d; csr_e[p] = e; }
}

// ---- layer-1 aggregate: wave per node, 8/4/1 tiered loop, logits inline (no max-sub) ----
// exp(v)/sum(exp(v)) == exp(v-m)/sum(exp(v-m)); epsilon rel-diff <= 1e-8
__global__ __launch_bounds__(256, 6)
void agg1_all(const int* __restrict__ csr_s, const int* __restrict__ rowptr,
              const float* __restrict__ es, const float* __restrict__ ed,
              const bf16* __restrict__ Wh1, bf16* __restrict__ h1) {
  int wid = threadIdx.x >> 6, lane = threadIdx.x & 63;
  int node = blockIdx.x * 4 + wid;
  if (node >= NN) return;
  int b = rowptr[node], e = rowptr[node + 1];
  if (b < 0) b = 0; if (e > EE) e = EE;
  int h = lane >> 4;
  float edh = ed[node * 4 + h];
  float sum = 0.f;
  float acc[8] = {};
  const bf16* W = Wh1 + lane * 8;
  int j = b;
  for (; j + 8 <= e; j += 8) {
    int s_[8];
    #pragma unroll
    for (int i = 0; i < 8; ++i) s_[i] = csr_s[j + i];
    float w[8];
    bf16x8 r[8];
    #pragma unroll
    for (int i = 0; i < 8; ++i) {
      w[i] = es[s_[i] * 4 + h];
      r[i] = *(const bf16x8*)(W + (size_t)s_[i] * C1);
    }
    #pragma unroll
    for (int i = 0; i < 8; ++i) {
      float p = __expf(lrelu(w[i] + edh));
      sum += p;
      #pragma unroll
      for (int k = 0; k < 8; ++k) acc[k] += p * (float)r[i][k];
    }
  }
  if (j + 4 <= e) {
    int s_[4];
    #pragma unroll
    for (int i = 0; i < 4; ++i) s_[i] = csr_s[j + i];
    float w[4];
    bf16x8 r[4];
    #pragma unroll
    for (int i = 0; i < 4; ++i) {
      w[i] = es[s_[i] * 4 + h];
      r[i] = *(const bf16x8*)(W + (size_t)s_[i] * C1);
    }
    #pragma unroll
    for (int i = 0; i < 4; ++i) {
      float p = __expf(lrelu(w[i] + edh));
      sum += p;
      #pragma unroll
      for (int k = 0; k < 8; ++k) acc[k] += p * (float)r[i][k];
    }
    j += 4;
  }
  for (; j < e; ++j) {
    int s0 = csr_s[j];
    float p = __expf(lrelu(es[s0 * 4 + h] + edh));
    bf16x8 r0 = *(const bf16x8*)(W + (size_t)s0 * C1);
    sum += p;
    #pragma unroll
    for (int k = 0; k < 8; ++k) acc[k] += p * (float)r0[k];
  }
  float scale = 1.f / (sum + 1e-8f);
  bf16x8 o;
  #pragma unroll
  for (int k = 0; k < 8; ++k) o[k] = (__bf16)eluf(acc[k] * scale);
  *(bf16x8*)(h1 + (size_t)node * C1 + lane * 8) = o;
}

// ---- layer-2 aggregate (H=1): 16-lane group per node, logits inline;
//      attention output fused (lane-parallel pass over the node's edges) ----
__global__ __launch_bounds__(256, 8)
void agg2_all(const int* __restrict__ csr_s, const int* __restrict__ csr_e,
              const int* __restrict__ rowptr,
              const float* __restrict__ es, const float* __restrict__ ed,
              const bf16* __restrict__ Wh2, bf16* __restrict__ h2p,
              float* __restrict__ out_attn) {
  int tid = threadIdx.x;
  int l16 = tid & 15;
  int node = blockIdx.x * 16 + (tid >> 4);
  if (node >= NN) return;
  int b = rowptr[node], e = rowptr[node + 1];
  if (b < 0) b = 0; if (e > EE) e = EE;
  float edn = ed[node];
  float sum = 0.f;
  float acc[8] = {};
  const bf16* W = Wh2 + l16 * 8;
  int j = b;
  for (; j + 4 <= e; j += 4) {
    int s_[4];
    #pragma unroll
    for (int i = 0; i < 4; ++i) s_[i] = csr_s[j + i];
    float w[4];
    bf16x8 r[4];
    #pragma unroll
    for (int i = 0; i < 4; ++i) {
      w[i] = es[s_[i]];
      r[i] = *(const bf16x8*)(W + (size_t)s_[i] * HID);
    }
    #pragma unroll
    for (int i = 0; i < 4; ++i) {
      float p = __expf(lrelu(w[i] + edn));
      sum += p;
      #pragma unroll
      for (int k = 0; k < 8; ++k) acc[k] += p * (float)r[i][k];
    }
  }
  for (; j < e; ++j) {
    int s0 = csr_s[j];
    float p = __expf(lrelu(es[s0] + edn));
    bf16x8 r0 = *(const bf16x8*)(W + (size_t)s0 * HID);
    sum += p;
    #pragma unroll
    for (int k = 0; k < 8; ++k) acc[k] += p * (float)r0[k];
  }
  float scale = 1.f / (sum + 1e-8f);
  bf16x8 o;
  #pragma unroll
  for (int k = 0; k < 8; ++k) o[k] = (__bf16)eluf(acc[k] * scale);
  *(bf16x8*)(h2p + (size_t)node * HID + l16 * 8) = o;
  for (int t = b + l16; t < e; t += 16) {
    int s0 = csr_s[t];
    int eid = csr_e[t];
    float p = __expf(lrelu(es[s0] + edn));
    if ((unsigned)eid < EE) out_attn[eid] = p * scale;
  }
}

// ---- read-only per-column stats: blockDim == C, thread-per-column ----
__global__ void stats_ro(const bf16* __restrict__ X, float* __restrict__ cs,
                         float* __restrict__ cq, int Nrows, int C) {
  int c = threadIdx.x;
  int rpb = (Nrows + gridDim.x - 1) / gridDim.x;
  int r0 = blockIdx.x * rpb, r1 = min(r0 + rpb, Nrows);
  float s = 0.f, s2 = 0.f;
  for (int r = r0; r < r1; ++r) {
    float v = b2f(X[(size_t)r * C + c]);
    s += v; s2 += v * v;
  }
  atomicAdd(&cs[c], s);
  atomicAdd(&cq[c], s2);
}

// ---- bn coefficients: sc = gamma*rstd, sh = beta - mu*gamma*rstd ----
__global__ void bn_coef(const float* __restrict__ cs, const float* __restrict__ cq,
                        const float* __restrict__ gamma, const float* __restrict__ beta,
                        float* __restrict__ sc, float* __restrict__ sh, int C, float invN) {
  int c = blockIdx.x * 256 + threadIdx.x;
  if (c >= C) return;
  float mu = cs[c] * invN;
  float var = cq[c] * invN - mu * mu;
  float g = rsqrtf(fmaxf(var, 0.f) + 1e-5f) * gamma[c];
  sc[c] = g;
  sh[c] = beta[c] - mu * g;
}

// ---- fused bn-apply (f32 out) + global mean pool (post-bn sums) ----
__global__ __launch_bounds__(256)
void poolbn_kernel(const bf16* __restrict__ h2p, const int* __restrict__ batch,
                   const float* __restrict__ sc, const float* __restrict__ sh,
                   float* __restrict__ out_h2, float* __restrict__ pooled) {
  int t = threadIdx.x;
  int f = t & 127, half = t >> 7;
  float scf = sc[f], shf = sh[f];
  int r0 = blockIdx.x * 32;
  int g_cur = -1;
  float acc = 0.f;
  #pragma unroll
  for (int i = 0; i < 16; ++i) {
    int r = r0 + half + 2 * i;
    if (r >= NN) break;
    int g = batch[r]; if ((unsigned)g >= NGR) g = 0;
    float v = b2f(h2p[(size_t)r * HID + f]) * scf + shf;
    out_h2[(size_t)r * HID + f] = v;
    if (g != g_cur) {
      if (g_cur >= 0) atomicAdd(&pooled[g_cur * HID + f], acc);
      g_cur = g; acc = 0.f;
    }
    acc += v;
  }
  if (g_cur >= 0) atomicAdd(&pooled[g_cur * HID + f], acc);
}

// ---- classifier (tiny, single block); counts computed in-kernel ----
__global__ void cls_kernel(const float* __restrict__ pooled, const int* __restrict__ batch,
                           const float* __restrict__ w1, const float* __restrict__ b1,
                           const float* __restrict__ w2, const float* __restrict__ b2,
                           float* __restrict__ out) {
  __shared__ float repr[NGR * HID];
  __shared__ float hid[NGR * 64];
  __shared__ float scnt[NGR];
  int t = threadIdx.x;  // 128
  if (t < NGR) {
    int g = t;
    int a = 0, b = NN;
    while (a < b) { int m = (a + b) >> 1; if (batch[m] < g) a = m + 1; else b = m; }
    int lb = a;
    a = 0; b = NN;
    while (a < b) { int m = (a + b) >> 1; if (batch[m] <= g) a = m + 1; else b = m; }
    scnt[t] = (float)(a - lb);
  }
  __syncthreads();
  for (int i = t; i < NGR * HID; i += 128) {
    int g = i >> 7;
    repr[i] = pooled[i] / fmaxf(scnt[g], 1.f);
  }
  __syncthreads();
  for (int i = t; i < NGR * 64; i += 128) {
    int g = i >> 6, j = i & 63;
    float s = b1[j];
    for (int c = 0; c < HID; ++c) s += repr[g * HID + c] * w1[c * 64 + j];
    hid[i] = fmaxf(s, 0.f);
  }
  __syncthreads();
  if (t < NGR * 2) {
    int g = t >> 1, k = t & 1;
    float s = b2[k];
    for (int j = 0; j < 64; ++j) s += hid[g * 64 + j] * w2[j * 2 + k];
    out[t] = s;
  }
}

// ---- edge importance from fused PQ (N,256): CSR order, 16-lane group per edge ----
__global__ __launch_bounds__(256)
void eimp_kernel(const int* __restrict__ csr_s, const int* __restrict__ csr_d,
                 const int* __restrict__ csr_e, const bf16* __restrict__ PQ,
                 const float* __restrict__ b1, const float* __restrict__ w2,
                 const float* __restrict__ b2, float* __restrict__ out) {
  int tid = threadIdx.x;
  int wave = tid >> 6, lane = tid & 63;
  int g = lane >> 4, l16 = lane & 15;
  int slot = blockIdx.x * 16 + wave * 4 + g;
  if (slot >= EE) return;
  int s = csr_s[slot]; if ((unsigned)s >= NN) s = 0;
  int d = csr_d[slot]; if ((unsigned)d >= NN) d = 0;
  int e = csr_e[slot]; if ((unsigned)e >= EE) return;
  bf16x8 p = *(const bf16x8*)(PQ + (size_t)s * 256 + l16 * 8);
  bf16x8 q = *(const bf16x8*)(PQ + (size_t)d * 256 + 128 + l16 * 8);
  float acc = 0.f;
  #pragma unroll
  for (int r = 0; r < 8; ++r) {
    int jj = l16 * 8 + r;
    float hh = (float)p[r] + (float)q[r] + b1[jj];
    hh = fmaxf(hh, 0.f);
    acc += hh * w2[jj];
  }
  #pragma unroll
  for (int off = 8; off > 0; off >>= 1) acc += __shfl_xor(acc, off);
  if (l16 == 0) {
    float z = acc + b2[0];
    out[e] = 1.f / (1.f + expf(-z));
  }
}

extern "C" void kernel_launch(void* const* d_in, const int* in_sizes, int n_in,
                              void* d_out, int out_size, void* d_ws, size_t ws_size,
                              hipStream_t stream) {
  const float* x      = (const float*)d_in[0];
  const int*   ei     = (const int*)d_in[1];
  const int*   batch  = (const int*)d_in[2];
  const float* W1     = (const float*)d_in[3];
  const float* a_src1 = (const float*)d_in[4];
  const float* a_dst1 = (const float*)d_in[5];
  const float* W2     = (const float*)d_in[6];
  const float* a_src2 = (const float*)d_in[7];
  const float* a_dst2 = (const float*)d_in[8];
  const float* bn1_g  = (const float*)d_in[9];
  const float* bn1_b  = (const float*)d_in[10];
  const float* bn2_g  = (const float*)d_in[11];
  const float* bn2_b  = (const float*)d_in[12];
  const float* cls_w1 = (const float*)d_in[13];
  const float* cls_b1 = (const float*)d_in[14];
  const float* cls_w2 = (const float*)d_in[15];
  const float* cls_b2 = (const float*)d_in[16];
  const float* ep_w1  = (const float*)d_in[17];
  const float* ep_b1  = (const float*)d_in[18];
  const float* ep_w2  = (const float*)d_in[19];
  const float* ep_b2  = (const float*)d_in[20];

  const int* srcp = ei;
  const int* dstp = ei + EE;

  // ---- workspace layout (bytes), peak ~110.5 MB, hazard-checked ----
  char* base = (char*)d_ws;
  bf16* xb   = (bf16*)(base);
  bf16* h1   = (bf16*)(base);
  bf16* Wh1  = (bf16*)(base + 51200000);
  bf16* Wh2  = (bf16*)(base + 51200000);
  bf16* PQ   = (bf16*)(base + 51200000);
  bf16* h2p  = (bf16*)(base + 76800000);
  float* es1   = (float*)(base + 102400000);    // (N,4) fully written by gemm1 epilogue
  float* ed1   = (float*)(base + 103200000);    // (N,4)
  float* es2   = (float*)(base + 104000000);    // (N)
  float* ed2   = (float*)(base + 104200000);    // (N)
  int*   deg   = (int*)(base + 104400000);      // (N)   [zero region start]
  float* stats = (float*)(base + 104600000);    // 3344 floats -> end 104,613,376
  float* cs1 = stats,        *cq1 = stats + 512;
  float* cs2 = stats + 1024, *cq2 = stats + 1152;
  float* pooled = stats + 1280;                 // 16*128
  float* sc1   = (float*)(base + 104613376);    // (512)
  float* sh1   = (float*)(base + 104615424);    // (512)
  float* sc2   = (float*)(base + 104617472);    // (128)
  float* sh2   = (float*)(base + 104617984);    // (128) -> 104,618,496
  int*   cursor= (int*)(base + 104818496);      // (N)
  int*   rowptr= (int*)(base + 105018496);      // (N+1) -> 105,218,500
  int*   bsum  = (int*)(base + 105218560);      // 256 + 256
  int*   boff  = bsum + 256;
  int*   csr_s = (int*)(base + 105220608);      // (E)
  int*   csr_d = (int*)(base + 106820608);      // (E)
  int*   csr_e = (int*)(base + 108420608);      // (E)
  bf16*  B1t   = (bf16*)(base + 110020608);     // (512,288)
  bf16*  B2t   = (bf16*)(base + 110315520);     // (128,512)
  bf16*  BPt   = (bf16*)(base + 110446592);     // (256,128) -> ends 110,512,128

  float* out        = (float*)d_out;
  float* out_logits = out;                          // 32
  float* out_h2     = out + 32;                     // N*128
  float* out_imp    = out + 32 + (size_t)NN * HID;  // E
  float* out_attn   = out_imp + EE;                 // E

  // zero deg+stats in one call (contiguous; 213,376 B = 53,344 words)
  zero_words<<<(53344 + 255) / 256, 256, 0, stream>>>((unsigned int*)deg, 53344);

  // merged prep: bf16 conversions / transposes
  prep_all<<<(PR3 + 255) / 256, 256, 0, stream>>>(x, W1, W2, ep_w1, xb, B1t, B2t, BPt);

  // CSR by destination; parallel 3-phase scan
  count_kernel<<<(EE + 255) / 256, 256, 0, stream>>>(dstp, deg, EE);
  scan_p1<<<SCAN_NB, 256, 0, stream>>>(deg, bsum);
  scan_p2<<<1, 256, 0, stream>>>(bsum, boff, rowptr + NN);
  scan_p3<<<SCAN_NB, 256, 0, stream>>>(deg, boff, rowptr, cursor);
  scatter_kernel<<<(EE + 255) / 256, 256, 0, stream>>>(srcp, dstp, cursor,
                                                       csr_s, csr_d, csr_e, EE);

  // ---- layer 1: GEMM (XCD-swizzled, edot fused) + aggregate ----
  const int NBY = (NN + 127) / 128;     // 391
  const int G8  = (NBY + 7) / 8;        // 49
  gemm_mfma<<<8 * G8 * 4, 256, 0, stream>>>(xb, B1t, Wh1, NN, KP1, C1,
                                            2, NBY, G8, nullptr, nullptr,
                                            a_src1, a_dst1, es1, ed1, 4);
  agg1_all<<<(NN + 3) / 4, 256, 0, stream>>>(csr_s, rowptr, es1, ed1, Wh1, h1);

  // read-only stats on ELU'd h1; bn folded into gemm2's A-staging
  stats_ro<<<400, C1, 0, stream>>>(h1, cs1, cq1, NN, C1);
  bn_coef<<<2, 256, 0, stream>>>(cs1, cq1, bn1_g, bn1_b, sc1, sh1, C1, 1.f / NN);

  // ---- layer 2 (edot fused into gemm2; attn output fused into agg2) ----
  gemm_mfma<<<8 * G8 * 1, 256, 0, stream>>>(h1, B2t, Wh2, NN, C1, HID,
                                            0, NBY, G8, sc1, sh1,
                                            a_src2, a_dst2, es2, ed2, 1);
  agg2_all<<<(NN + 15) / 16, 256, 0, stream>>>(csr_s, csr_e, rowptr, es2, ed2,
                                               Wh2, h2p, out_attn);

  stats_ro<<<400, HID, 0, stream>>>(h2p, cs2, cq2, NN, HID);
  bn_coef<<<1, 256, 0, stream>>>(cs2, cq2, bn2_g, bn2_b, sc2, sh2, HID, 1.f / NN);

  // fused bn-out + pool (post-bn sums), then classifier (counts in-kernel)
  poolbn_kernel<<<(NN + 31) / 32, 256, 0, stream>>>(h2p, batch, sc2, sh2, out_h2, pooled);
  cls_kernel<<<1, 128, 0, stream>>>(pooled, batch, cls_w1, cls_b1, cls_w2, cls_b2,
                                    out_logits);

  // PQ gemm reads pre-bn h2p with bn2 fused into A-staging (no edot)
  gemm_mfma<<<8 * G8 * 2, 256, 0, stream>>>(h2p, BPt, PQ, NN, HID, 256,
                                            1, NBY, G8, sc2, sh2,
                                            nullptr, nullptr, nullptr, nullptr, 0);
  eimp_kernel<<<(EE + 15) / 16, 256, 0, stream>>>(csr_s, csr_d, csr_e, PQ,
                                                  ep_b1, ep_w2, ep_b2, out_imp);
}

// Round 16
// 571.434 us; speedup vs baseline: 1.1254x; 1.0281x over previous
//
#include <hip/hip_runtime.h>
#include <hip/hip_bf16.h>
#include <math.h>

typedef __hip_bfloat16 bf16;
typedef __bf16 bf16x8 __attribute__((ext_vector_type(8)));
typedef float f32x4 __attribute__((ext_vector_type(4)));

#define NN 50000
#define EE 400000
#define FIN 262
#define KP1 288   /* FIN padded to multiple of 32 */
#define HID 128
#define NH 4
#define C1 512   /* HID*NH */
#define NGR 16
#define SCAN_NB ((NN + 255) / 256)   /* 196 */

__device__ __forceinline__ float b2f(bf16 x){ return __bfloat162float(x); }
__device__ __forceinline__ bf16 f2b(float x){ return __float2bfloat16(x); }
__device__ __forceinline__ float lrelu(float v){ return v >= 0.f ? v : 0.2f * v; }
__device__ __forceinline__ float eluf(float v){ return v > 0.f ? v : expm1f(v); }

// direct global->LDS (16B per lane; LDS dest = wave-uniform base + lane*16)
__device__ __forceinline__ void gload16(const bf16* g, __bf16* l) {
  __builtin_amdgcn_global_load_lds(
      (const __attribute__((address_space(1))) void*)g,
      (__attribute__((address_space(3))) void*)l, 16, 0, 0);
}

__global__ void zero_words(unsigned int* __restrict__ p, int n) {
  int i = blockIdx.x * 256 + threadIdx.x;
  if (i < n) p[i] = 0u;
}

// ================= MFMA GEMM: C(M,N) = A(M,K) @ B(K,N) =================
// Staging: B (and A when no fused bn) via global_load_lds with PRE-SWIZZLED
// per-lane global source (linear LDS dest, chunk-XOR applied to src column);
// A with fused bn (sc/sh) stays reg-staged. 1-deep lookahead; LDS 32 KiB.
// OOB A-rows load from a 64B zeroed pad (no predication on gload path).
// XCD-aware 1D grid; pad blocks exit before any barrier.
__global__ __launch_bounds__(256)
void gemm_mfma(const bf16* __restrict__ A, const bf16* __restrict__ Bt,
               bf16* __restrict__ C, int M, int K, int Ncols,
               int nbxShift, int nby, int g8, const bf16* __restrict__ zpad,
               const float* __restrict__ sc, const float* __restrict__ sh,
               const float* __restrict__ av, const float* __restrict__ bv,
               float* __restrict__ esp, float* __restrict__ edp, int dstride) {
  __shared__ __align__(16) __bf16 As[2][128 * 32];
  __shared__ __align__(16) __bf16 Bs[2][128 * 32];
  int s = blockIdx.x;
  int xcd = s & 7;
  int j = s >> 3;
  int by = xcd * g8 + (j >> nbxShift);
  int bx = j & ((1 << nbxShift) - 1);
  if (by >= nby) return;              // uniform exit, before any barrier
  int bm = by * 128, bn = bx * 128;
  int tid = threadIdx.x;
  int wave = tid >> 6, lane = tid & 63;
  int quad = lane >> 4, l16 = lane & 15;
  int wm = (wave >> 1) * 64, wn = (wave & 1) * 64;
  int rowA = (tid * 8) >> 5;          // 0..63 (each thread also covers rowA+64)
  int colT = (tid * 8) & 31;
  int swW = ((rowA >> 1) & 3) << 3;   // chunk swizzle (same for rowA+64)
  int scol = colT ^ swW;              // pre-swizzled source column
  int waveBase = wave * 512;          // wave-uniform LDS element base
  int gm0 = bm + rowA, gm1 = bm + rowA + 64;
  int gn0 = bn + rowA, gn1 = bn + rowA + 64;
  const uint4 zz = {0u, 0u, 0u, 0u};

  f32x4 acc[4][4];
  #pragma unroll
  for (int i = 0; i < 4; ++i)
    #pragma unroll
    for (int jj = 0; jj < 4; ++jj)
      acc[i][jj] = (f32x4){0.f, 0.f, 0.f, 0.f};

  uint4 a0, a1;   // reg staging (bn path only)

  auto xf = [&](uint4 v, int kb) -> uint4 {   // kb = k0 + colT
    bf16x8 a8 = *(bf16x8*)&v;
    float4 c0 = *(const float4*)(sc + kb);
    float4 c1 = *(const float4*)(sc + kb + 4);
    float4 h0 = *(const float4*)(sh + kb);
    float4 h1 = *(const float4*)(sh + kb + 4);
    bf16x8 t8;
    t8[0] = (__bf16)((float)a8[0] * c0.x + h0.x);
    t8[1] = (__bf16)((float)a8[1] * c0.y + h0.y);
    t8[2] = (__bf16)((float)a8[2] * c0.z + h0.z);
    t8[3] = (__bf16)((float)a8[3] * c0.w + h0.w);
    t8[4] = (__bf16)((float)a8[4] * c1.x + h1.x);
    t8[5] = (__bf16)((float)a8[5] * c1.y + h1.y);
    t8[6] = (__bf16)((float)a8[6] * c1.z + h1.z);
    t8[7] = (__bf16)((float)a8[7] * c1.w + h1.w);
    return *(uint4*)&t8;
  };
  auto stageB = [&](int buf, int k0) {
    gload16(Bt + (size_t)gn0 * K + k0 + scol, &Bs[buf][waveBase]);
    gload16(Bt + (size_t)gn1 * K + k0 + scol, &Bs[buf][2048 + waveBase]);
  };
  auto stageAdir = [&](int buf, int k0) {
    const bf16* g0 = (gm0 < M) ? (A + (size_t)gm0 * K + k0 + scol) : zpad;
    const bf16* g1 = (gm1 < M) ? (A + (size_t)gm1 * K + k0 + scol) : zpad;
    gload16(g0, &As[buf][waveBase]);
    gload16(g1, &As[buf][2048 + waveBase]);
  };
  auto ldA = [&](int k0) {
    a0 = (gm0 < M) ? *(const uint4*)(A + (size_t)gm0 * K + k0 + colT) : zz;
    a1 = (gm1 < M) ? *(const uint4*)(A + (size_t)gm1 * K + k0 + colT) : zz;
  };
  auto stA = [&](int buf, int k0) {
    int cw = colT ^ swW;
    *(uint4*)(&As[buf][rowA * 32 + cw])        = xf(a0, k0 + colT);
    *(uint4*)(&As[buf][(rowA + 64) * 32 + cw]) = xf(a1, k0 + colT);
  };
  auto mm = [&](int cur) {
    bf16x8 af[4], bfr[4];
    #pragma unroll
    for (int i = 0; i < 4; ++i) {
      int r = wm + i * 16 + l16;
      af[i] = *(const bf16x8*)(&As[cur][r * 32 + ((quad << 3) ^ (((r >> 1) & 3) << 3))]);
    }
    #pragma unroll
    for (int jj = 0; jj < 4; ++jj) {
      int r = wn + jj * 16 + l16;
      bfr[jj] = *(const bf16x8*)(&Bs[cur][r * 32 + ((quad << 3) ^ (((r >> 1) & 3) << 3))]);
    }
    #pragma unroll
    for (int i = 0; i < 4; ++i)
      #pragma unroll
      for (int jj = 0; jj < 4; ++jj)
        acc[i][jj] = __builtin_amdgcn_mfma_f32_16x16x32_bf16(af[i], bfr[jj], acc[i][jj], 0, 0, 0);
  };

  int nt = K >> 5;
  stageB(0, 0);
  if (sc == nullptr) {
    stageAdir(0, 0);
  } else {
    ldA(0);
    stA(0, 0);
  }
  __syncthreads();

  for (int t = 0; t < nt; ++t) {
    int cur = t & 1;
    bool more = (t + 1 < nt);
    int k1 = (t + 1) << 5;
    if (more) {
      stageB(cur ^ 1, k1);
      if (sc == nullptr) stageAdir(cur ^ 1, k1);
      else ldA(k1);
    }
    mm(cur);
    if (more && sc != nullptr) stA(cur ^ 1, k1);
    __syncthreads();   // drains vmcnt/lgkm -> next buffer ready
  }

  // C write
  #pragma unroll
  for (int i = 0; i < 4; ++i) {
    #pragma unroll
    for (int r = 0; r < 4; ++r) {
      int gm = bm + wm + i * 16 + quad * 4 + r;
      if (gm >= M) continue;
      #pragma unroll
      for (int jj = 0; jj < 4; ++jj) {
        int gn = bn + wn + jj * 16 + l16;
        C[(size_t)gm * Ncols + gn] = f2b(acc[i][jj][r]);
      }
    }
  }

  // fused edot epilogue: per-row dual dot over this block's 128 cols.
  if (esp) {
    float* red = (float*)&As[0][0];   // 128 rows x {waveHalf} x {es,ed} = 2 KB
    float avj[4], bvj[4];
    #pragma unroll
    for (int jj = 0; jj < 4; ++jj) {
      int gn = bn + wn + jj * 16 + l16;
      avj[jj] = av[gn]; bvj[jj] = bv[gn];
    }
    #pragma unroll
    for (int i = 0; i < 4; ++i)
      #pragma unroll
      for (int r = 0; r < 4; ++r) {
        float pa = 0.f, pb = 0.f;
        #pragma unroll
        for (int jj = 0; jj < 4; ++jj) {
          float v = acc[i][jj][r];
          pa += v * avj[jj]; pb += v * bvj[jj];
        }
        #pragma unroll
        for (int off = 8; off > 0; off >>= 1) {
          pa += __shfl_xor(pa, off);
          pb += __shfl_xor(pb, off);
        }
        if (l16 == 0) {
          int rl = wm + i * 16 + quad * 4 + r;   // 0..127
          red[rl * 4 + (wave & 1) * 2 + 0] = pa;
          red[rl * 4 + (wave & 1) * 2 + 1] = pb;
        }
      }
    __syncthreads();
    if (tid < 128) {
      int gm = bm + tid;
      if (gm < M) {
        int hoff = (dstride == 4) ? (bn >> 7) : 0;
        esp[gm * dstride + hoff] = red[tid * 4 + 0] + red[tid * 4 + 2];
        edp[gm * dstride + hoff] = red[tid * 4 + 1] + red[tid * 4 + 3];
      }
    }
  }
}

// ---- merged prep: conv_x | b1t | b2t | bpt (range-dispatched) ----
#define PR0 (NN * KP1)                 /* 14,400,000 */
#define PR1 (PR0 + C1 * KP1)           /* 14,547,456 */
#define PR2 (PR1 + HID * C1)           /* 14,612,992 */
#define PR3 (PR2 + 256 * HID)          /* 14,645,760 */
__global__ void prep_all(const float* __restrict__ x, const float* __restrict__ W1,
                         const float* __restrict__ W2, const float* __restrict__ epw1,
                         bf16* __restrict__ xb, bf16* __restrict__ B1t,
                         bf16* __restrict__ B2t, bf16* __restrict__ BPt) {
  int i = blockIdx.x * 256 + threadIdx.x;
  if (i < PR0) {
    int row = i / KP1, col = i - row * KP1;
    xb[i] = (col < FIN) ? f2b(x[(size_t)row * FIN + col]) : f2b(0.f);
  } else if (i < PR1) {
    int j = i - PR0;
    int n = j / KP1, k = j - n * KP1;   // n = h*128 + o
    int h = n >> 7, o = n & 127;
    B1t[j] = (k < FIN) ? f2b(W1[((size_t)h * FIN + k) * HID + o]) : f2b(0.f);
  } else if (i < PR2) {
    int j = i - PR1;
    int n = j >> 9, k = j & 511;
    B2t[j] = f2b(W2[(size_t)k * HID + n]);
  } else if (i < PR3) {
    int j = i - PR2;
    int n = j >> 7, k = j & 127;
    float v = (n < 128) ? epw1[(size_t)k * HID + n]
                        : epw1[(size_t)(128 + k) * HID + (n - 128)];
    BPt[j] = f2b(v);
  }
}

// ---------------- CSR build ----------------
__global__ void count_kernel(const int* __restrict__ dst, int* __restrict__ deg, int E) {
  int e = blockIdx.x * blockDim.x + threadIdx.x;
  if (e >= E) return;
  int d = dst[e];
  if ((unsigned)d < NN) atomicAdd(&deg[d], 1);
}

__global__ void scan_p1(const int* __restrict__ deg, int* __restrict__ bsum) {
  __shared__ int s[256];
  int t = threadIdx.x;
  int i = blockIdx.x * 256 + t;
  s[t] = (i < NN) ? deg[i] : 0;
  __syncthreads();
  #pragma unroll
  for (int off = 128; off > 0; off >>= 1) {
    if (t < off) s[t] += s[t + off];
    __syncthreads();
  }
  if (t == 0) bsum[blockIdx.x] = s[0];
}
__global__ void scan_p2(const int* __restrict__ bsum, int* __restrict__ boff,
                        int* __restrict__ total_out) {
  __shared__ int s[256];
  int t = threadIdx.x;
  int v = (t < SCAN_NB) ? bsum[t] : 0;
  s[t] = v;
  __syncthreads();
  #pragma unroll
  for (int off = 1; off < 256; off <<= 1) {
    int add = (t >= off) ? s[t - off] : 0;
    __syncthreads();
    s[t] += add;
    __syncthreads();
  }
  if (t < SCAN_NB) boff[t] = s[t] - v;   // exclusive
  if (t == 255) total_out[0] = s[255];   // rowptr[NN]
}
__global__ void scan_p3(const int* __restrict__ deg, const int* __restrict__ boff,
                        int* __restrict__ rowptr, int* __restrict__ cursor) {
  __shared__ int s[256];
  int t = threadIdx.x;
  int i = blockIdx.x * 256 + t;
  int v = (i < NN) ? deg[i] : 0;
  s[t] = v;
  __syncthreads();
  #pragma unroll
  for (int off = 1; off < 256; off <<= 1) {
    int add = (t >= off) ? s[t - off] : 0;
    __syncthreads();
    s[t] += add;
    __syncthreads();
  }
  if (i < NN) {
    int pos = boff[blockIdx.x] + s[t] - v;   // exclusive
    rowptr[i] = pos;
    cursor[i] = pos;
  }
}

__global__ void scatter_kernel(const int* __restrict__ src, const int* __restrict__ dst,
                               int* __restrict__ cursor, int* __restrict__ csr_s,
                               int* __restrict__ csr_d, int* __restrict__ csr_e, int E) {
  int e = blockIdx.x * blockDim.x + threadIdx.x;
  if (e >= E) return;
  int d = dst[e];
  if ((unsigned)d >= NN) return;
  int s = src[e]; if ((unsigned)s >= NN) s = 0;
  int p = atomicAdd(&cursor[d], 1);
  if ((unsigned)p < (unsigned)E) { csr_s[p] = s; csr_d[p] = d; csr_e[p] = e; }
}

// ---- layer-1 aggregate: wave per node, 8/4/1 tiered loop, logits inline (no max-sub) ----
__global__ __launch_bounds__(256, 6)
void agg1_all(const int* __restrict__ csr_s, const int* __restrict__ rowptr,
              const float* __restrict__ es, const float* __restrict__ ed,
              const bf16* __restrict__ Wh1, bf16* __restrict__ h1) {
  int wid = threadIdx.x >> 6, lane = threadIdx.x & 63;
  int node = blockIdx.x * 4 + wid;
  if (node >= NN) return;
  int b = rowptr[node], e = rowptr[node + 1];
  if (b < 0) b = 0; if (e > EE) e = EE;
  int h = lane >> 4;
  float edh = ed[node * 4 + h];
  float sum = 0.f;
  float acc[8] = {};
  const bf16* W = Wh1 + lane * 8;
  int j = b;
  for (; j + 8 <= e; j += 8) {
    int s_[8];
    #pragma unroll
    for (int i = 0; i < 8; ++i) s_[i] = csr_s[j + i];
    float w[8];
    bf16x8 r[8];
    #pragma unroll
    for (int i = 0; i < 8; ++i) {
      w[i] = es[s_[i] * 4 + h];
      r[i] = *(const bf16x8*)(W + (size_t)s_[i] * C1);
    }
    #pragma unroll
    for (int i = 0; i < 8; ++i) {
      float p = __expf(lrelu(w[i] + edh));
      sum += p;
      #pragma unroll
      for (int k = 0; k < 8; ++k) acc[k] += p * (float)r[i][k];
    }
  }
  if (j + 4 <= e) {
    int s_[4];
    #pragma unroll
    for (int i = 0; i < 4; ++i) s_[i] = csr_s[j + i];
    float w[4];
    bf16x8 r[4];
    #pragma unroll
    for (int i = 0; i < 4; ++i) {
      w[i] = es[s_[i] * 4 + h];
      r[i] = *(const bf16x8*)(W + (size_t)s_[i] * C1);
    }
    #pragma unroll
    for (int i = 0; i < 4; ++i) {
      float p = __expf(lrelu(w[i] + edh));
      sum += p;
      #pragma unroll
      for (int k = 0; k < 8; ++k) acc[k] += p * (float)r[i][k];
    }
    j += 4;
  }
  for (; j < e; ++j) {
    int s0 = csr_s[j];
    float p = __expf(lrelu(es[s0 * 4 + h] + edh));
    bf16x8 r0 = *(const bf16x8*)(W + (size_t)s0 * C1);
    sum += p;
    #pragma unroll
    for (int k = 0; k < 8; ++k) acc[k] += p * (float)r0[k];
  }
  float scale = 1.f / (sum + 1e-8f);
  bf16x8 o;
  #pragma unroll
  for (int k = 0; k < 8; ++k) o[k] = (__bf16)eluf(acc[k] * scale);
  *(bf16x8*)(h1 + (size_t)node * C1 + lane * 8) = o;
}

// ---- layer-2 aggregate (H=1): 16-lane group per node, logits inline;
//      attention output fused (lane-parallel pass over the node's edges) ----
__global__ __launch_bounds__(256, 8)
void agg2_all(const int* __restrict__ csr_s, const int* __restrict__ csr_e,
              const int* __restrict__ rowptr,
              const float* __restrict__ es, const float* __restrict__ ed,
              const bf16* __restrict__ Wh2, bf16* __restrict__ h2p,
              float* __restrict__ out_attn) {
  int tid = threadIdx.x;
  int l16 = tid & 15;
  int node = blockIdx.x * 16 + (tid >> 4);
  if (node >= NN) return;
  int b = rowptr[node], e = rowptr[node + 1];
  if (b < 0) b = 0; if (e > EE) e = EE;
  float edn = ed[node];
  float sum = 0.f;
  float acc[8] = {};
  const bf16* W = Wh2 + l16 * 8;
  int j = b;
  for (; j + 4 <= e; j += 4) {
    int s_[4];
    #pragma unroll
    for (int i = 0; i < 4; ++i) s_[i] = csr_s[j + i];
    float w[4];
    bf16x8 r[4];
    #pragma unroll
    for (int i = 0; i < 4; ++i) {
      w[i] = es[s_[i]];
      r[i] = *(const bf16x8*)(W + (size_t)s_[i] * HID);
    }
    #pragma unroll
    for (int i = 0; i < 4; ++i) {
      float p = __expf(lrelu(w[i] + edn));
      sum += p;
      #pragma unroll
      for (int k = 0; k < 8; ++k) acc[k] += p * (float)r[i][k];
    }
  }
  for (; j < e; ++j) {
    int s0 = csr_s[j];
    float p = __expf(lrelu(es[s0] + edn));
    bf16x8 r0 = *(const bf16x8*)(W + (size_t)s0 * HID);
    sum += p;
    #pragma unroll
    for (int k = 0; k < 8; ++k) acc[k] += p * (float)r0[k];
  }
  float scale = 1.f / (sum + 1e-8f);
  bf16x8 o;
  #pragma unroll
  for (int k = 0; k < 8; ++k) o[k] = (__bf16)eluf(acc[k] * scale);
  *(bf16x8*)(h2p + (size_t)node * HID + l16 * 8) = o;
  for (int t = b + l16; t < e; t += 16) {
    int s0 = csr_s[t];
    int eid = csr_e[t];
    float p = __expf(lrelu(es[s0] + edn));
    if ((unsigned)eid < EE) out_attn[eid] = p * scale;
  }
}

// ---- read-only per-column stats: blockDim == C, thread-per-column ----
__global__ void stats_ro(const bf16* __restrict__ X, float* __restrict__ cs,
                         float* __restrict__ cq, int Nrows, int C) {
  int c = threadIdx.x;
  int rpb = (Nrows + gridDim.x - 1) / gridDim.x;
  int r0 = blockIdx.x * rpb, r1 = min(r0 + rpb, Nrows);
  float s = 0.f, s2 = 0.f;
  for (int r = r0; r < r1; ++r) {
    float v = b2f(X[(size_t)r * C + c]);
    s += v; s2 += v * v;
  }
  atomicAdd(&cs[c], s);
  atomicAdd(&cq[c], s2);
}

// ---- bn coefficients: sc = gamma*rstd, sh = beta - mu*gamma*rstd ----
__global__ void bn_coef(const float* __restrict__ cs, const float* __restrict__ cq,
                        const float* __restrict__ gamma, const float* __restrict__ beta,
                        float* __restrict__ sc, float* __restrict__ sh, int C, float invN) {
  int c = blockIdx.x * 256 + threadIdx.x;
  if (c >= C) return;
  float mu = cs[c] * invN;
  float var = cq[c] * invN - mu * mu;
  float g = rsqrtf(fmaxf(var, 0.f) + 1e-5f) * gamma[c];
  sc[c] = g;
  sh[c] = beta[c] - mu * g;
}

// ---- fused bn-apply (f32 out) + global mean pool (post-bn sums) ----
__global__ __launch_bounds__(256)
void poolbn_kernel(const bf16* __restrict__ h2p, const int* __restrict__ batch,
                   const float* __restrict__ sc, const float* __restrict__ sh,
                   float* __restrict__ out_h2, float* __restrict__ pooled) {
  int t = threadIdx.x;
  int f = t & 127, half = t >> 7;
  float scf = sc[f], shf = sh[f];
  int r0 = blockIdx.x * 32;
  int g_cur = -1;
  float acc = 0.f;
  #pragma unroll
  for (int i = 0; i < 16; ++i) {
    int r = r0 + half + 2 * i;
    if (r >= NN) break;
    int g = batch[r]; if ((unsigned)g >= NGR) g = 0;
    float v = b2f(h2p[(size_t)r * HID + f]) * scf + shf;
    out_h2[(size_t)r * HID + f] = v;
    if (g != g_cur) {
      if (g_cur >= 0) atomicAdd(&pooled[g_cur * HID + f], acc);
      g_cur = g; acc = 0.f;
    }
    acc += v;
  }
  if (g_cur >= 0) atomicAdd(&pooled[g_cur * HID + f], acc);
}

// ---- classifier (tiny, single block); counts computed in-kernel ----
__global__ void cls_kernel(const float* __restrict__ pooled, const int* __restrict__ batch,
                           const float* __restrict__ w1, const float* __restrict__ b1,
                           const float* __restrict__ w2, const float* __restrict__ b2,
                           float* __restrict__ out) {
  __shared__ float repr[NGR * HID];
  __shared__ float hid[NGR * 64];
  __shared__ float scnt[NGR];
  int t = threadIdx.x;  // 128
  if (t < NGR) {
    int g = t;
    int a = 0, b = NN;
    while (a < b) { int m = (a + b) >> 1; if (batch[m] < g) a = m + 1; else b = m; }
    int lb = a;
    a = 0; b = NN;
    while (a < b) { int m = (a + b) >> 1; if (batch[m] <= g) a = m + 1; else b = m; }
    scnt[t] = (float)(a - lb);
  }
  __syncthreads();
  for (int i = t; i < NGR * HID; i += 128) {
    int g = i >> 7;
    repr[i] = pooled[i] / fmaxf(scnt[g], 1.f);
  }
  __syncthreads();
  for (int i = t; i < NGR * 64; i += 128) {
    int g = i >> 6, j = i & 63;
    float s = b1[j];
    for (int c = 0; c < HID; ++c) s += repr[g * HID + c] * w1[c * 64 + j];
    hid[i] = fmaxf(s, 0.f);
  }
  __syncthreads();
  if (t < NGR * 2) {
    int g = t >> 1, k = t & 1;
    float s = b2[k];
    for (int j = 0; j < 64; ++j) s += hid[g * 64 + j] * w2[j * 2 + k];
    out[t] = s;
  }
}

// ---- edge importance from fused PQ (N,256): CSR order, 16-lane group per edge ----
__global__ __launch_bounds__(256)
void eimp_kernel(const int* __restrict__ csr_s, const int* __restrict__ csr_d,
                 const int* __restrict__ csr_e, const bf16* __restrict__ PQ,
                 const float* __restrict__ b1, const float* __restrict__ w2,
                 const float* __restrict__ b2, float* __restrict__ out) {
  int tid = threadIdx.x;
  int wave = tid >> 6, lane = tid & 63;
  int g = lane >> 4, l16 = lane & 15;
  int slot = blockIdx.x * 16 + wave * 4 + g;
  if (slot >= EE) return;
  int s = csr_s[slot]; if ((unsigned)s >= NN) s = 0;
  int d = csr_d[slot]; if ((unsigned)d >= NN) d = 0;
  int e = csr_e[slot]; if ((unsigned)e >= EE) return;
  bf16x8 p = *(const bf16x8*)(PQ + (size_t)s * 256 + l16 * 8);
  bf16x8 q = *(const bf16x8*)(PQ + (size_t)d * 256 + 128 + l16 * 8);
  float acc = 0.f;
  #pragma unroll
  for (int r = 0; r < 8; ++r) {
    int jj = l16 * 8 + r;
    float hh = (float)p[r] + (float)q[r] + b1[jj];
    hh = fmaxf(hh, 0.f);
    acc += hh * w2[jj];
  }
  #pragma unroll
  for (int off = 8; off > 0; off >>= 1) acc += __shfl_xor(acc, off);
  if (l16 == 0) {
    float z = acc + b2[0];
    out[e] = 1.f / (1.f + expf(-z));
  }
}

extern "C" void kernel_launch(void* const* d_in, const int* in_sizes, int n_in,
                              void* d_out, int out_size, void* d_ws, size_t ws_size,
                              hipStream_t stream) {
  const float* x      = (const float*)d_in[0];
  const int*   ei     = (const int*)d_in[1];
  const int*   batch  = (const int*)d_in[2];
  const float* W1     = (const float*)d_in[3];
  const float* a_src1 = (const float*)d_in[4];
  const float* a_dst1 = (const float*)d_in[5];
  const float* W2     = (const float*)d_in[6];
  const float* a_src2 = (const float*)d_in[7];
  const float* a_dst2 = (const float*)d_in[8];
  const float* bn1_g  = (const float*)d_in[9];
  const float* bn1_b  = (const float*)d_in[10];
  const float* bn2_g  = (const float*)d_in[11];
  const float* bn2_b  = (const float*)d_in[12];
  const float* cls_w1 = (const float*)d_in[13];
  const float* cls_b1 = (const float*)d_in[14];
  const float* cls_w2 = (const float*)d_in[15];
  const float* cls_b2 = (const float*)d_in[16];
  const float* ep_w1  = (const float*)d_in[17];
  const float* ep_b1  = (const float*)d_in[18];
  const float* ep_w2  = (const float*)d_in[19];
  const float* ep_b2  = (const float*)d_in[20];

  const int* srcp = ei;
  const int* dstp = ei + EE;

  // ---- workspace layout (bytes), peak ~110.5 MB, hazard-checked ----
  char* base = (char*)d_ws;
  bf16* xb   = (bf16*)(base);
  bf16* h1   = (bf16*)(base);
  bf16* Wh1  = (bf16*)(base + 51200000);
  bf16* Wh2  = (bf16*)(base + 51200000);
  bf16* PQ   = (bf16*)(base + 51200000);
  bf16* h2p  = (bf16*)(base + 76800000);
  float* es1   = (float*)(base + 102400000);    // (N,4) fully written by gemm1 epilogue
  float* ed1   = (float*)(base + 103200000);    // (N,4)
  float* es2   = (float*)(base + 104000000);    // (N)
  float* ed2   = (float*)(base + 104200000);    // (N)
  int*   deg   = (int*)(base + 104400000);      // (N)   [zero region start]
  float* stats = (float*)(base + 104600000);    // 3344 floats -> end 104,613,376
  float* cs1 = stats,        *cq1 = stats + 512;
  float* cs2 = stats + 1024, *cq2 = stats + 1152;
  float* pooled = stats + 1280;                 // 16*128
  float* sc1   = (float*)(base + 104613376);    // (512)
  float* sh1   = (float*)(base + 104615424);    // (512)
  float* sc2   = (float*)(base + 104617472);    // (128)
  float* sh2   = (float*)(base + 104617984);    // (128) -> 104,618,496
  bf16*  zpad  = (bf16*)(base + 104650000);     // 64 B zero pad (inside zero region)
  int*   cursor= (int*)(base + 104818496);      // (N)
  int*   rowptr= (int*)(base + 105018496);      // (N+1) -> 105,218,500
  int*   bsum  = (int*)(base + 105218560);      // 256 + 256
  int*   boff  = bsum + 256;
  int*   csr_s = (int*)(base + 105220608);      // (E)
  int*   csr_d = (int*)(base + 106820608);      // (E)
  int*   csr_e = (int*)(base + 108420608);      // (E)
  bf16*  B1t   = (bf16*)(base + 110020608);     // (512,288)
  bf16*  B2t   = (bf16*)(base + 110315520);     // (128,512)
  bf16*  BPt   = (bf16*)(base + 110446592);     // (256,128) -> ends 110,512,128

  float* out        = (float*)d_out;
  float* out_logits = out;                          // 32
  float* out_h2     = out + 32;                     // N*128
  float* out_imp    = out + 32 + (size_t)NN * HID;  // E
  float* out_attn   = out_imp + EE;                 // E

  // zero deg..zpad in one call ([104,400,000, 104,700,064) = 75,016 words;
  // sc/sh inside are overwritten by bn_coef before use)
  zero_words<<<(75016 + 255) / 256, 256, 0, stream>>>((unsigned int*)deg, 75016);

  // merged prep: bf16 conversions / transposes
  prep_all<<<(PR3 + 255) / 256, 256, 0, stream>>>(x, W1, W2, ep_w1, xb, B1t, B2t, BPt);

  // CSR by destination; parallel 3-phase scan
  count_kernel<<<(EE + 255) / 256, 256, 0, stream>>>(dstp, deg, EE);
  scan_p1<<<SCAN_NB, 256, 0, stream>>>(deg, bsum);
  scan_p2<<<1, 256, 0, stream>>>(bsum, boff, rowptr + NN);
  scan_p3<<<SCAN_NB, 256, 0, stream>>>(deg, boff, rowptr, cursor);
  scatter_kernel<<<(EE + 255) / 256, 256, 0, stream>>>(srcp, dstp, cursor,
                                                       csr_s, csr_d, csr_e, EE);

  // ---- layer 1: GEMM (gload_lds staging, XCD-swizzled, edot fused) + aggregate ----
  const int NBY = (NN + 127) / 128;     // 391
  const int G8  = (NBY + 7) / 8;        // 49
  gemm_mfma<<<8 * G8 * 4, 256, 0, stream>>>(xb, B1t, Wh1, NN, KP1, C1,
                                            2, NBY, G8, zpad, nullptr, nullptr,
                                            a_src1, a_dst1, es1, ed1, 4);
  agg1_all<<<(NN + 3) / 4, 256, 0, stream>>>(csr_s, rowptr, es1, ed1, Wh1, h1);

  // read-only stats on ELU'd h1; bn folded into gemm2's A-staging
  stats_ro<<<400, C1, 0, stream>>>(h1, cs1, cq1, NN, C1);
  bn_coef<<<2, 256, 0, stream>>>(cs1, cq1, bn1_g, bn1_b, sc1, sh1, C1, 1.f / NN);

  // ---- layer 2 (edot fused into gemm2; attn output fused into agg2) ----
  gemm_mfma<<<8 * G8 * 1, 256, 0, stream>>>(h1, B2t, Wh2, NN, C1, HID,
                                            0, NBY, G8, zpad, sc1, sh1,
                                            a_src2, a_dst2, es2, ed2, 1);
  agg2_all<<<(NN + 15) / 16, 256, 0, stream>>>(csr_s, csr_e, rowptr, es2, ed2,
                                               Wh2, h2p, out_attn);

  stats_ro<<<400, HID, 0, stream>>>(h2p, cs2, cq2, NN, HID);
  bn_coef<<<1, 256, 0, stream>>>(cs2, cq2, bn2_g, bn2_b, sc2, sh2, HID, 1.f / NN);

  // fused bn-out + pool (post-bn sums), then classifier (counts in-kernel)
  poolbn_kernel<<<(NN + 31) / 32, 256, 0, stream>>>(h2p, batch, sc2, sh2, out_h2, pooled);
  cls_kernel<<<1, 128, 0, stream>>>(pooled, batch, cls_w1, cls_b1, cls_w2, cls_b2,
                                    out_logits);

  // PQ gemm reads pre-bn h2p with bn2 fused into A-staging (no edot)
  gemm_mfma<<<8 * G8 * 2, 256, 0, stream>>>(h2p, BPt, PQ, NN, HID, 256,
                                            1, NBY, G8, zpad, sc2, sh2,
                                            nullptr, nullptr, nullptr, nullptr, 0);
  eimp_kernel<<<(EE + 15) / 16, 256, 0, stream>>>(csr_s, csr_d, csr_e, PQ,
                                                  ep_b1, ep_w2, ep_b2, out_imp);
}